// Round 14
// baseline (635.185 us; speedup 1.0000x reference)
//
#include <hip/hip_runtime.h>
#include <math.h>

namespace {

constexpr int NQn = 100000, NAn = 200000, NKn = 200000;
constexpr int EPc = 100000, ENc = 100000;
constexpr int ETOT = 2400000, NSEG = 600000;

// ---- workspace layout (float element offsets) ----
constexpr long XSB_OFF  = 0;            // 16M floats = 32M bf16 xs
constexpr long OUTB_OFF = 16000000;     // 16M floats = 32M bf16 attn out
constexpr long QBF_OFF  = 32000000;     // 16M floats = 32M bf16 q
constexpr long KV_OFF   = 48000000;     // 38.4M floats = 600064 x 128 bf16
constexpr long ZB_OFF   = 86500000;     // 9.6M floats = 300000 x 64 bf16 (zq|za)
constexpr long WTB_OFF  = 96200000;     // bf16 transposed weights
constexpr long WFB_OFF  = 96250000;     // fp32 fused kv bias (512)
constexpr long INT_OFF  = 96300000;     // int region
// int offsets within (int*)(ws + INT_OFF):
constexpr long DEG_I  = 0;
constexpr long CUR_I  = 600000;
constexpr long OFFS_I = 1200000;
constexpr long PART_I = 1800064;
constexpr long CSRC_I = 1801088;

// wtb ushort offsets (LINT no longer stored; lin transposes in-kernel)
constexpr int QT_U   = 0;        // 3 x 64 x 64
constexpr int AT_U   = 12288;    // 3 x 64 x 64
constexpr int WFT_U  = 24576;    // 4 x 128 x 64

__constant__ long c_rbase[4] = {0, 200000, 300032, 400064};

typedef __attribute__((ext_vector_type(8))) short bf16x8;
typedef __attribute__((ext_vector_type(4))) float f32x4;

__device__ inline f32x4 mfma16(bf16x8 a, bf16x8 b, f32x4 c) {
    return __builtin_amdgcn_mfma_f32_16x16x32_bf16(a, b, c, 0, 0, 0);
}

__device__ inline float gelu_f(float x) {
    return 0.5f * x * (1.0f + erff(x * 0.7071067811865475f));
}
__device__ inline float bf2f(unsigned short u) {
    return __uint_as_float(((unsigned)u) << 16);
}
__device__ inline unsigned short f2bf(float f) {
    unsigned u = __float_as_uint(f);
    return (unsigned short)((u + 0x7fffu + ((u >> 16) & 1u)) >> 16);
}

// block -> node-type mapping, 128-row tiles: counts {782, 1563, 1563}
__device__ inline void type_of_block128(int b, int& t, int& n0) {
    if (b < 782)       { t = 0; n0 = b * 128; }
    else if (b < 2345) { t = 1; n0 = (b - 782) * 128; }
    else               { t = 2; n0 = (b - 2345) * 128; }
}
// block -> node-type mapping, 64-row tiles: counts {1563, 3125, 3125}
__device__ inline void type_of_block64(int b, int& t, int& n0) {
    if (b < 1563)      { t = 0; n0 = b * 64; }
    else if (b < 4688) { t = 1; n0 = (b - 1563) * 64; }
    else               { t = 2; n0 = (b - 4688) * 64; }
}

// ---- staging helpers (XOR-swizzled LDS, 16B chunks) ----
template<int K>
__device__ inline void stage_bf16(unsigned short* lds, const unsigned short* src,
                                  int n0, int n, int tid)
{
    constexpr int CPR = K / 8;
    for (int c = tid; c < 128 * CPR; c += 256) {
        int row = c / CPR, kc = c % CPR;
        int node = n0 + row; if (node > n - 1) node = n - 1;
        uint4 v = *(const uint4*)&src[(long)node * K + kc * 8];
        int byte = (row * K + kc * 8) * 2;
        *(uint4*)((char*)lds + (byte ^ ((row & 7) << 4))) = v;
    }
}

// bf16 input + gelu applied during staging (K=64)
__device__ inline void stage_out_gelu(unsigned short* lds, const unsigned short* src,
                                      int n0, int n, int tid)
{
    for (int c = tid; c < 128 * 8; c += 256) {
        int row = c >> 3, kc = c & 7;
        int node = n0 + row; if (node > n - 1) node = n - 1;
        uint4 v = *(const uint4*)&src[(long)node * 64 + kc * 8];
        float f0 = gelu_f(bf2f((unsigned short)(v.x & 0xffffu)));
        float f1 = gelu_f(bf2f((unsigned short)(v.x >> 16)));
        float f2 = gelu_f(bf2f((unsigned short)(v.y & 0xffffu)));
        float f3 = gelu_f(bf2f((unsigned short)(v.y >> 16)));
        float f4 = gelu_f(bf2f((unsigned short)(v.z & 0xffffu)));
        float f5 = gelu_f(bf2f((unsigned short)(v.z >> 16)));
        float f6 = gelu_f(bf2f((unsigned short)(v.w & 0xffffu)));
        float f7 = gelu_f(bf2f((unsigned short)(v.w >> 16)));
        uint4 o;
        o.x = (unsigned)f2bf(f0) | ((unsigned)f2bf(f1) << 16);
        o.y = (unsigned)f2bf(f2) | ((unsigned)f2bf(f3) << 16);
        o.z = (unsigned)f2bf(f4) | ((unsigned)f2bf(f5) << 16);
        o.w = (unsigned)f2bf(f6) | ((unsigned)f2bf(f7) << 16);
        int byte = (row * 64 + kc * 8) * 2;
        *(uint4*)((char*)lds + (byte ^ ((row & 7) << 4))) = o;
    }
}

template<int K, int ROWS>
__device__ inline void stage_f32(unsigned short* lds, const float* src,
                                 int n0, int n, int tid)
{
    constexpr int CPR = K / 8;
    for (int c = tid; c < ROWS * CPR; c += 256) {
        int row = c / CPR, kc = c % CPR;
        int node = n0 + row; if (node > n - 1) node = n - 1;
        const float* sp = &src[(long)node * K + kc * 8];
        float4 f0 = *(const float4*)sp, f1 = *(const float4*)(sp + 4);
        uint4 v;
        v.x = (unsigned)f2bf(f0.x) | ((unsigned)f2bf(f0.y) << 16);
        v.y = (unsigned)f2bf(f0.z) | ((unsigned)f2bf(f0.w) << 16);
        v.z = (unsigned)f2bf(f1.x) | ((unsigned)f2bf(f1.y) << 16);
        v.w = (unsigned)f2bf(f1.z) | ((unsigned)f2bf(f1.w) << 16);
        int byte = (row * K + kc * 8) * 2;
        *(uint4*)((char*)lds + (byte ^ ((row & 7) << 4))) = v;
    }
}

template<int N, int K>
__device__ inline void stage_w(unsigned short* lds, const unsigned short* wt, int tid)
{
    constexpr int CPR = K / 8;
    for (int c = tid; c < N * CPR; c += 256) {
        int nr = c / CPR, kc = c % CPR;
        uint4 v = *(const uint4*)&wt[nr * K + kc * 8];
        int byte = (nr * K + kc * 8) * 2;
        *(uint4*)((char*)lds + (byte ^ ((nr & 7) << 4))) = v;
    }
}

// transpose raw fp32 weight [128][64] (k-major) into LDS [nn][kk] bf16, swizzled
__device__ inline void stage_wT_f32(unsigned short* lds, const float* w, int tid)
{
    for (int c = tid * 4; c < 8192; c += 1024) {
        int kk = c >> 6, nn0 = c & 63;
        float4 v = *(const float4*)&w[kk * 64 + nn0];
        float vals[4] = {v.x, v.y, v.z, v.w};
        #pragma unroll
        for (int i = 0; i < 4; ++i) {
            int nn = nn0 + i;
            int byte = (nn * 128 + kk) * 2;
            *(unsigned short*)((char*)lds + (byte ^ ((nn & 7) << 4))) = f2bf(vals[i]);
        }
    }
}

// ---- MFMA core (TRANSPOSED operand order): wave w covers rows
// [w*16*MF, w*16*MF + 16*MF). acc[mf][nf]: col(lane&15)=node,
// rows=(lane>>4)*4+i = 4 consecutive out cols.
template<int K, int NF, int MF>
__device__ inline void mfma_coreT(const unsigned short* ldsX, const unsigned short* ldsW,
                                  f32x4 (&acc)[MF][NF], int lane, int w)
{
    const int lrow = lane & 15, lk = (lane >> 4) * 8;
    #pragma unroll
    for (int ks = 0; ks < K / 32; ++ks) {
        bf16x8 a[MF], b[NF];
        #pragma unroll
        for (int mf = 0; mf < MF; ++mf) {
            int row = w * (16 * MF) + mf * 16 + lrow;
            int byte = (row * K + ks * 32 + lk) * 2;
            a[mf] = *(const bf16x8*)((const char*)ldsX + (byte ^ ((row & 7) << 4)));
        }
        #pragma unroll
        for (int nf = 0; nf < NF; ++nf) {
            int nr = nf * 16 + lrow;
            int byte = (nr * K + ks * 32 + lk) * 2;
            b[nf] = *(const bf16x8*)((const char*)ldsW + (byte ^ ((nr & 7) << 4)));
        }
        #pragma unroll
        for (int mf = 0; mf < MF; ++mf)
            #pragma unroll
            for (int nf = 0; nf < NF; ++nf)
                acc[mf][nf] = mfma16(b[nf], a[mf], acc[mf][nf]);   // swapped!
    }
}

// ---- edge id -> (segment, source) mapping -----------------------------------
__device__ inline void edge_map(int gid,
                                const int* __restrict__ s0, const int* __restrict__ d0,
                                const int* __restrict__ s1, const int* __restrict__ d1,
                                const int* __restrict__ s2, const int* __restrict__ d2,
                                const int* __restrict__ s3, const int* __restrict__ d3,
                                int& seg, int& s)
{
    if (gid < 800000)       { seg = d0[gid];                    s = s0[gid]; }
    else if (gid < 1600000) { seg = 100000 + d1[gid - 800000];  s = s1[gid - 800000]; }
    else if (gid < 2000000) { seg = 300000 + d2[gid - 1600000]; s = s2[gid - 1600000]; }
    else                    { seg = 500000 + d3[gid - 2000000]; s = s3[gid - 2000000]; }
}

// ---- mega-fused stage 1: lin GEMM + weight prep + CSR degree count ----------
// blocks [0,7813): lin (reads RAW lin_w, transposes in LDS itself)
// [7813,7817): fused rel weights; [7817,7913): q/a transposes;
// [7913, 7913+9375): csr degree count
__global__ void __launch_bounds__(256)
lin_prep_count(const float* __restrict__ xq, const float* __restrict__ xa,
               const float* __restrict__ xk, const float* __restrict__ lin_w,
               const float* __restrict__ lin_b, unsigned short* __restrict__ xsb,
               const float* __restrict__ q_w, const float* __restrict__ a_w,
               const float* __restrict__ kw, const float* __restrict__ kb,
               const float* __restrict__ vw, const float* __restrict__ vb,
               const float* __restrict__ a_rel, const float* __restrict__ m_rel,
               unsigned short* __restrict__ wtb, float* __restrict__ wfb,
               const int* __restrict__ d0, const int* __restrict__ d1,
               const int* __restrict__ d2, const int* __restrict__ d3,
               int* __restrict__ deg)
{
    __shared__ unsigned short ldsX[64 * 128];   // 16 KB
    __shared__ unsigned short ldsW[64 * 128];   // 16 KB
    const int b = blockIdx.x;
    const int tid = threadIdx.x;

    if (b < 7813) {
        // ---- lin: xs_bf16 = relu(x @ lin_w + lin_b), 64-row tile
        int t, n0; type_of_block64(b, t, n0);
        const int cnt[3] = {NQn, NAn, NKn};
        const long noff[3] = {0, NQn, NQn + NAn};
        const float* X = (t == 0) ? xq : (t == 1) ? xa : xk;
        const int n = cnt[t];

        stage_wT_f32(ldsW, lin_w + (long)t * 8192, tid);
        stage_f32<128, 64>(ldsX, X, n0, n, tid);
        __syncthreads();

        const int w = tid >> 6, lane = tid & 63;
        f32x4 acc[1][4] = {};
        mfma_coreT<128, 4, 1>(ldsX, ldsW, acc, lane, w);

        const int nodeL = lane & 15, colG = (lane >> 4) * 4;
        int node = n0 + w * 16 + nodeL;
        if (node < n) {
            #pragma unroll
            for (int nf = 0; nf < 4; ++nf) {
                int col0 = nf * 16 + colG;
                float4 bv = *(const float4*)&lin_b[t * 64 + col0];
                ushort4 o;
                o.x = f2bf(fmaxf(acc[0][nf][0] + bv.x, 0.f));
                o.y = f2bf(fmaxf(acc[0][nf][1] + bv.y, 0.f));
                o.z = f2bf(fmaxf(acc[0][nf][2] + bv.z, 0.f));
                o.w = f2bf(fmaxf(acc[0][nf][3] + bv.w, 0.f));
                *(ushort4*)&xsb[(noff[t] + node) * 64 + col0] = o;
            }
        }
    } else if (b < 7817) {
        // ---- fused relation weights, transposed bf16
        const int r = b - 7813;
        const int st_tab[4] = {2, 0, 0, 1};
        const int st = st_tab[r];
        for (int idx = tid; idx < 8192; idx += 256) {
            int d = idx >> 7, c = idx & 127;
            int i = c >> 1, which = c & 1;
            int h = i >> 5, e = i & 31;
            const float* w   = (which ? vw : kw) + st * 4096;
            const float* rel = (which ? m_rel : a_rel) + r * 2048;
            float s = 0.f;
            #pragma unroll
            for (int c32 = 0; c32 < 32; ++c32)
                s += w[d * 64 + h * 32 + c32] * rel[h * 1024 + c32 * 32 + e];
            wtb[WFT_U + r * 8192 + c * 64 + d] = f2bf(s);
        }
        for (int idx = tid; idx < 128; idx += 256) {
            int i = idx >> 1, which = idx & 1;
            int h = i >> 5, e = i & 31;
            const float* bb  = (which ? vb : kb) + st * 64;
            const float* rel = (which ? m_rel : a_rel) + r * 2048;
            float s = 0.f;
            #pragma unroll
            for (int c32 = 0; c32 < 32; ++c32)
                s += bb[h * 32 + c32] * rel[h * 1024 + c32 * 32 + e];
            wfb[r * 128 + idx] = s;
        }
    } else if (b < 7913) {
        // ---- q_w / a_w transposes to bf16
        int i = (b - 7817) * 256 + tid;
        if (i < 12288) {
            int t = i / 4096, rem = i % 4096, nn = rem >> 6, kk = rem & 63;
            wtb[QT_U + i] = f2bf(q_w[t * 4096 + kk * 64 + nn]);
        } else {
            int j = i - 12288;
            int t = j / 4096, rem = j % 4096, nn = rem >> 6, kk = rem & 63;
            wtb[AT_U + j] = f2bf(a_w[t * 4096 + kk * 64 + nn]);
        }
    } else {
        // ---- CSR degree count
        int gid = (b - 7913) * 256 + tid;
        if (gid < 800000)       atomicAdd(&deg[d0[gid]], 1);
        else if (gid < 1600000) atomicAdd(&deg[100000 + d1[gid - 800000]], 1);
        else if (gid < 2000000) atomicAdd(&deg[300000 + d2[gid - 1600000]], 1);
        else if (gid < 2400000) atomicAdd(&deg[500000 + d3[gid - 2000000]], 1);
    }
}

// ---- mega-fused stage 2: CSR fill (latency-bound) + q/kv GEMMs (compute) ----
// 13286 blocks. b<9376: even -> qkv(b/2), odd -> fill(b/2);
// b>=9376: qkv(4688 + b - 9376). Fill: 4688 blocks x 256 thr x 2 edges.
__global__ void __launch_bounds__(256)
fill_qkv(const int* __restrict__ s0, const int* __restrict__ d0,
         const int* __restrict__ s1, const int* __restrict__ d1,
         const int* __restrict__ s2, const int* __restrict__ d2,
         const int* __restrict__ s3, const int* __restrict__ d3,
         const int* __restrict__ off, int* __restrict__ cur, int* __restrict__ csrc,
         const unsigned short* __restrict__ xsb, const unsigned short* __restrict__ wtb,
         const float* __restrict__ q_b, const float* __restrict__ wfb,
         unsigned short* __restrict__ qbf, unsigned short* __restrict__ kvb)
{
    __shared__ unsigned short ldsX[128 * 64];   // 16 KB
    __shared__ unsigned short ldsW[128 * 64];   // 16 KB
    const int b = blockIdx.x;
    const int tid = threadIdx.x;

    int qkvb, fillb;
    if (b < 9376) {
        if (b & 1) { fillb = b >> 1; qkvb = -1; }
        else       { qkvb = b >> 1;  fillb = -1; }
    } else { qkvb = 4688 + (b - 9376); fillb = -1; }

    if (fillb >= 0) {
        int base = fillb * 256 + tid;
        if (base < 1200000) {
            int segA, sA, segB, sB;
            edge_map(base,           s0, d0, s1, d1, s2, d2, s3, d3, segA, sA);
            edge_map(base + 1200000, s0, d0, s1, d1, s2, d2, s3, d3, segB, sB);
            int oA = off[segA], oB = off[segB];
            int slotA = oA + atomicAdd(&cur[segA], 1);
            int slotB = oB + atomicAdd(&cur[segB], 1);
            csrc[slotA] = sA;
            csrc[slotB] = sB;
        }
        return;
    }

    const int cnt[3] = {NQn, NAn, NKn};
    const long noff[3] = {0, NQn, NQn + NAn};
    const int w = tid >> 6, lane = tid & 63;
    const int nodeL = lane & 15, colG = (lane >> 4) * 4;

    if (qkvb < 3908) {
        // ---- q product ----
        int t, n0; type_of_block128(qkvb, t, n0);
        const int n = cnt[t];
        stage_bf16<64>(ldsX, xsb + noff[t] * 64, n0, n, tid);
        stage_w<64, 64>(ldsW, wtb + QT_U + t * 4096, tid);
        __syncthreads();

        f32x4 acc[2][4] = {};
        mfma_coreT<64, 4, 2>(ldsX, ldsW, acc, lane, w);
        #pragma unroll
        for (int mf = 0; mf < 2; ++mf) {
            int node = n0 + w * 32 + mf * 16 + nodeL;
            if (node < n) {
                #pragma unroll
                for (int nf = 0; nf < 4; ++nf) {
                    int col0 = nf * 16 + colG;
                    float4 bv = *(const float4*)&q_b[t * 64 + col0];
                    ushort4 o;
                    o.x = f2bf(acc[mf][nf][0] + bv.x);
                    o.y = f2bf(acc[mf][nf][1] + bv.y);
                    o.z = f2bf(acc[mf][nf][2] + bv.z);
                    o.w = f2bf(acc[mf][nf][3] + bv.w);
                    *(ushort4*)&qbf[(noff[t] + node) * 64 + col0] = o;
                }
            }
        }
    } else {
        // ---- kv product ----
        int kb = qkvb - 3908, r, lb;
        if (kb < 1563)      { r = 0; lb = kb; }
        else if (kb < 2345) { r = 1; lb = kb - 1563; }
        else if (kb < 3127) { r = 2; lb = kb - 2345; }
        else                { r = 3; lb = kb - 3127; }
        const int stt[4] = {2, 0, 0, 1};
        const int st = stt[r];
        const int n0 = lb * 128;
        const int n = cnt[st];
        const long rb = c_rbase[r];

        stage_bf16<64>(ldsX, xsb + noff[st] * 64, n0, n, tid);
        stage_w<128, 64>(ldsW, wtb + WFT_U + r * 8192, tid);
        __syncthreads();

        f32x4 acc[2][8] = {};
        mfma_coreT<64, 8, 2>(ldsX, ldsW, acc, lane, w);
        #pragma unroll
        for (int mf = 0; mf < 2; ++mf) {
            int node = n0 + w * 32 + mf * 16 + nodeL;
            if (node < n) {
                #pragma unroll
                for (int nf = 0; nf < 8; ++nf) {
                    int col0 = nf * 16 + colG;
                    float4 bv = *(const float4*)&wfb[r * 128 + col0];
                    ushort4 o;
                    o.x = f2bf(acc[mf][nf][0] + bv.x);
                    o.y = f2bf(acc[mf][nf][1] + bv.y);
                    o.z = f2bf(acc[mf][nf][2] + bv.z);
                    o.w = f2bf(acc[mf][nf][3] + bv.w);
                    *(ushort4*)&kvb[(rb + node) * 128 + col0] = o;
                }
            }
        }
    }
}

// ---- head: z = beta*(gelu(out) @ a_w + a_b) + (1-beta)*xs; bf16 z copies for pred
__global__ void __launch_bounds__(256)
head_mfma(const unsigned short* __restrict__ outb, const unsigned short* __restrict__ xsb,
          const unsigned short* __restrict__ wtb, const float* __restrict__ a_b,
          const float* __restrict__ skip, float* __restrict__ z,
          unsigned short* __restrict__ zb)
{
    __shared__ unsigned short ldsX[128 * 64];
    __shared__ unsigned short ldsW[64 * 64];
    int t, n0; type_of_block128(blockIdx.x, t, n0);
    const int cnt[3] = {NQn, NAn, NKn};
    const long noff[3] = {0, NQn, NQn + NAn};
    const long zoff[3] = {200000L, 6600000L, 19400000L};
    const int n = cnt[t];
    const int tid = threadIdx.x;

    stage_w<64, 64>(ldsW, wtb + AT_U + t * 4096, tid);
    stage_out_gelu(ldsX, outb + noff[t] * 64, n0, n, tid);
    __syncthreads();

    const int w = tid >> 6, lane = tid & 63;
    f32x4 acc[2][4] = {};
    mfma_coreT<64, 4, 2>(ldsX, ldsW, acc, lane, w);

    const float beta = 1.f / (1.f + expf(-skip[t]));
    const int nodeL = lane & 15, colG = (lane >> 4) * 4;
    #pragma unroll
    for (int mf = 0; mf < 2; ++mf) {
        int node = n0 + w * 32 + mf * 16 + nodeL;
        if (node < n) {
            #pragma unroll
            for (int nf = 0; nf < 4; ++nf) {
                int col0 = nf * 16 + colG;
                float4 bv = *(const float4*)&a_b[t * 64 + col0];
                ushort4 rv = *(const ushort4*)&xsb[(noff[t] + node) * 64 + col0];
                float4 o;
                o.x = beta * (acc[mf][nf][0] + bv.x) + (1.f - beta) * bf2f(rv.x);
                o.y = beta * (acc[mf][nf][1] + bv.y) + (1.f - beta) * bf2f(rv.y);
                o.z = beta * (acc[mf][nf][2] + bv.z) + (1.f - beta) * bf2f(rv.z);
                o.w = beta * (acc[mf][nf][3] + bv.w) + (1.f - beta) * bf2f(rv.w);
                *(float4*)&z[zoff[t] + (long)node * 64 + col0] = o;
                if (t < 2) {
                    ushort4 p;
                    p.x = f2bf(o.x); p.y = f2bf(o.y); p.z = f2bf(o.z); p.w = f2bf(o.w);
                    long zrow = (t == 0) ? (long)node : 100000L + node;
                    *(ushort4*)&zb[zrow * 64 + col0] = p;
                }
            }
        }
    }
}

// ---- scans -------------------------------------------------------------------
__global__ void scan1(const int* __restrict__ in, int* __restrict__ out,
                      int* __restrict__ part, int n)
{
    __shared__ int lds[256];
    const int tid = threadIdx.x;
    const int base = blockIdx.x * 1024 + tid * 4;
    int v[4];
    #pragma unroll
    for (int k = 0; k < 4; ++k) v[k] = (base + k < n) ? in[base + k] : 0;
    int tsum = v[0] + v[1] + v[2] + v[3];
    lds[tid] = tsum;
    __syncthreads();
    for (int off = 1; off < 256; off <<= 1) {
        int t = (tid >= off) ? lds[tid - off] : 0;
        __syncthreads();
        lds[tid] += t;
        __syncthreads();
    }
    int excl = lds[tid] - tsum;
    #pragma unroll
    for (int k = 0; k < 4; ++k) {
        if (base + k < n) out[base + k] = excl;
        excl += v[k];
    }
    if (tid == 255) part[blockIdx.x] = lds[255];
}

__global__ void scan2(int* __restrict__ part, int nb)   // nb <= 1024
{
    __shared__ int lds[256];
    const int tid = threadIdx.x;
    const int base = tid * 4;
    int v[4];
    #pragma unroll
    for (int k = 0; k < 4; ++k) v[k] = (base + k < nb) ? part[base + k] : 0;
    int tsum = v[0] + v[1] + v[2] + v[3];
    lds[tid] = tsum;
    __syncthreads();
    for (int off = 1; off < 256; off <<= 1) {
        int t = (tid >= off) ? lds[tid - off] : 0;
        __syncthreads();
        lds[tid] += t;
        __syncthreads();
    }
    int excl = lds[tid] - tsum;
    #pragma unroll
    for (int k = 0; k < 4; ++k) {
        if (base + k < nb) part[base + k] = excl;
        excl += v[k];
    }
}

__global__ void scan3(int* __restrict__ off, const int* __restrict__ part, int n, int E)
{
    int i = blockIdx.x * 256 + threadIdx.x;
    if (i < n) off[i] += part[i >> 10];
    if (i == 0) off[n] = E;
}

// ---- fused attention: one 16-lane group per destination node ----------------
// No max-tracking (shift-invariant softmax; alphas O(1), clamped at 115 in exp2
// domain). p_rel*scale*log2e folded into q. 4-edge ILP per iteration.
__device__ inline void attn_node(const int* __restrict__ csrc, int begin, int end,
                                 const unsigned short* __restrict__ kvt,
                                 const float qv[4], int j, float res[4])
{
    float ss = 0.f, a0 = 0.f, a1 = 0.f, a2 = 0.f, a3 = 0.f;

    for (int t = begin; t < end; t += 4) {
        bool v1 = (t + 1 < end), v2 = (t + 2 < end), v3 = (t + 3 < end);
        int s0 = csrc[t];
        int s1 = csrc[v1 ? t + 1 : t];
        int s2 = csrc[v2 ? t + 2 : t];
        int s3 = csrc[v3 ? t + 3 : t];
        uint4 k0 = *(const uint4*)(kvt + (long)s0 * 128 + j * 8);
        uint4 k1 = *(const uint4*)(kvt + (long)s1 * 128 + j * 8);
        uint4 k2 = *(const uint4*)(kvt + (long)s2 * 128 + j * 8);
        uint4 k3 = *(const uint4*)(kvt + (long)s3 * 128 + j * 8);

        float p0 = __uint_as_float(k0.x << 16) * qv[0] + __uint_as_float(k0.y << 16) * qv[1]
                 + __uint_as_float(k0.z << 16) * qv[2] + __uint_as_float(k0.w << 16) * qv[3];
        float p1 = __uint_as_float(k1.x << 16) * qv[0] + __uint_as_float(k1.y << 16) * qv[1]
                 + __uint_as_float(k1.z << 16) * qv[2] + __uint_as_float(k1.w << 16) * qv[3];
        float p2 = __uint_as_float(k2.x << 16) * qv[0] + __uint_as_float(k2.y << 16) * qv[1]
                 + __uint_as_float(k2.z << 16) * qv[2] + __uint_as_float(k2.w << 16) * qv[3];
        float p3 = __uint_as_float(k3.x << 16) * qv[0] + __uint_as_float(k3.y << 16) * qv[1]
                 + __uint_as_float(k3.z << 16) * qv[2] + __uint_as_float(k3.w << 16) * qv[3];

        p0 += __shfl_xor(p0, 1);  p1 += __shfl_xor(p1, 1);
        p2 += __shfl_xor(p2, 1);  p3 += __shfl_xor(p3, 1);
        p0 += __shfl_xor(p0, 2);  p1 += __shfl_xor(p1, 2);
        p2 += __shfl_xor(p2, 2);  p3 += __shfl_xor(p3, 2);
        p0 += __shfl_xor(p0, 4);  p1 += __shfl_xor(p1, 4);
        p2 += __shfl_xor(p2, 4);  p3 += __shfl_xor(p3, 4);

        float w0 = exp2f(fminf(p0, 115.f));
        float w1 = v1 ? exp2f(fminf(p1, 115.f)) : 0.f;
        float w2 = v2 ? exp2f(fminf(p2, 115.f)) : 0.f;
        float w3 = v3 ? exp2f(fminf(p3, 115.f)) : 0.f;

        ss += (w0 + w1) + (w2 + w3);
        a0 += w0 * __uint_as_float(k0.x & 0xffff0000u) + w1 * __uint_as_float(k1.x & 0xffff0000u)
            + w2 * __uint_as_float(k2.x & 0xffff0000u) + w3 * __uint_as_float(k3.x & 0xffff0000u);
        a1 += w0 * __uint_as_float(k0.y & 0xffff0000u) + w1 * __uint_as_float(k1.y & 0xffff0000u)
            + w2 * __uint_as_float(k2.y & 0xffff0000u) + w3 * __uint_as_float(k3.y & 0xffff0000u);
        a2 += w0 * __uint_as_float(k0.z & 0xffff0000u) + w1 * __uint_as_float(k1.z & 0xffff0000u)
            + w2 * __uint_as_float(k2.z & 0xffff0000u) + w3 * __uint_as_float(k3.z & 0xffff0000u);
        a3 += w0 * __uint_as_float(k0.w & 0xffff0000u) + w1 * __uint_as_float(k1.w & 0xffff0000u)
            + w2 * __uint_as_float(k2.w & 0xffff0000u) + w3 * __uint_as_float(k3.w & 0xffff0000u);
    }

    float inv = 1.f / (ss + 1e-16f);
    res[0] = a0 * inv; res[1] = a1 * inv; res[2] = a2 * inv; res[3] = a3 * inv;
}

__global__ void __launch_bounds__(256)
attn_all(const int* __restrict__ off, const int* __restrict__ csrc,
         const unsigned short* __restrict__ qbf, const unsigned short* __restrict__ kv,
         const float* __restrict__ prel, float scale, unsigned short* __restrict__ outb)
{
    const int tid = threadIdx.x;
    const int nid = blockIdx.x * 16 + (tid >> 4);   // 16 nodes per block
    const int j = tid & 15;
    const int h = j >> 3;
    const float l2e = 1.4426950408889634f;

    long row; int segA, segB = -1; long kbA, kbB = 0; float psA, psB = 0.f;
    if (nid < 100000) {
        row = nid;
        segA = nid;            kbA = c_rbase[0]; psA = prel[0 + h] * scale * l2e;
        segB = 500000 + nid;   kbB = c_rbase[3]; psB = prel[6 + h] * scale * l2e;
    } else if (nid < 300000) {
        int kk = nid - 100000;
        row = 300000 + kk;
        segA = 100000 + kk;    kbA = c_rbase[1]; psA = prel[2 + h] * scale * l2e;
    } else {
        int aa = nid - 300000;
        row = 100000 + aa;
        segA = 300000 + aa;    kbA = c_rbase[2]; psA = prel[4 + h] * scale * l2e;
    }

    ushort4 q4 = *(const ushort4*)&qbf[row * 64 + 4 * j];
    float qraw[4] = {bf2f(q4.x), bf2f(q4.y), bf2f(q4.z), bf2f(q4.w)};

    float res[4];
    {
        float qv[4] = {qraw[0] * psA, qraw[1] * psA, qraw[2] * psA, qraw[3] * psA};
        attn_node(csrc, off[segA], off[segA + 1], kv + kbA * 128, qv, j, res);
    }
    if (segB >= 0) {
        float qv[4] = {qraw[0] * psB, qraw[1] * psB, qraw[2] * psB, qraw[3] * psB};
        float r2[4];
        attn_node(csrc, off[segB], off[segB + 1], kv + kbB * 128, qv, j, r2);
        res[0] += r2[0]; res[1] += r2[1]; res[2] += r2[2]; res[3] += r2[3];
    }

    ushort4 o;
    o.x = f2bf(res[0]); o.y = f2bf(res[1]); o.z = f2bf(res[2]); o.w = f2bf(res[3]);
    *(ushort4*)&outb[row * 64 + 4 * j] = o;
}

// ---- link prediction (bf16 z gathers) ---------------------------------------
__global__ void pred_all(const int* __restrict__ psrc, const int* __restrict__ pdst,
                         const int* __restrict__ nsrc, const int* __restrict__ ndst,
                         const unsigned short* __restrict__ zb, float* __restrict__ out)
{
    int t = blockIdx.x * 256 + threadIdx.x;
    int g = t >> 3, lane = t & 7;
    if (g >= EPc + ENc) return;
    int s, d;
    if (g < EPc) { s = psrc[g]; d = pdst[g]; }
    else         { int gg = g - EPc; s = nsrc[gg]; d = ndst[gg]; }
    uint4 zs = *(const uint4*)&zb[(long)s * 64 + lane * 8];
    uint4 zd = *(const uint4*)&zb[(100000L + d) * 64 + lane * 8];
    float p = 0.f;
    p += bf2f((unsigned short)(zs.x & 0xffffu)) * bf2f((unsigned short)(zd.x & 0xffffu));
    p += bf2f((unsigned short)(zs.x >> 16))     * bf2f((unsigned short)(zd.x >> 16));
    p += bf2f((unsigned short)(zs.y & 0xffffu)) * bf2f((unsigned short)(zd.y & 0xffffu));
    p += bf2f((unsigned short)(zs.y >> 16))     * bf2f((unsigned short)(zd.y >> 16));
    p += bf2f((unsigned short)(zs.z & 0xffffu)) * bf2f((unsigned short)(zd.z & 0xffffu));
    p += bf2f((unsigned short)(zs.z >> 16))     * bf2f((unsigned short)(zd.z >> 16));
    p += bf2f((unsigned short)(zs.w & 0xffffu)) * bf2f((unsigned short)(zd.w & 0xffffu));
    p += bf2f((unsigned short)(zs.w >> 16))     * bf2f((unsigned short)(zd.w >> 16));
    p += __shfl_xor(p, 1);
    p += __shfl_xor(p, 2);
    p += __shfl_xor(p, 4);
    if (lane == 0) out[g] = 1.f / (1.f + expf(-p));
}

} // namespace

extern "C" void kernel_launch(void* const* d_in, const int* in_sizes, int n_in,
                              void* d_out, int out_size, void* d_ws, size_t ws_size,
                              hipStream_t stream)
{
    const float* xq    = (const float*)d_in[0];
    const float* xa    = (const float*)d_in[1];
    const float* xk    = (const float*)d_in[2];
    const float* lin_w = (const float*)d_in[3];
    const float* lin_b = (const float*)d_in[4];
    const float* k_w   = (const float*)d_in[5];
    const float* k_b   = (const float*)d_in[6];
    const float* q_w   = (const float*)d_in[7];
    const float* q_b   = (const float*)d_in[8];
    const float* v_w   = (const float*)d_in[9];
    const float* v_b   = (const float*)d_in[10];
    const float* a_w   = (const float*)d_in[11];
    const float* a_b   = (const float*)d_in[12];
    const float* a_rel = (const float*)d_in[13];
    const float* m_rel = (const float*)d_in[14];
    const float* p_rel = (const float*)d_in[15];
    const float* skip  = (const float*)d_in[16];
    const int* esrc[4] = {(const int*)d_in[17], (const int*)d_in[19], (const int*)d_in[21], (const int*)d_in[23]};
    const int* edst[4] = {(const int*)d_in[18], (const int*)d_in[20], (const int*)d_in[22], (const int*)d_in[24]};
    const int* pos_src = (const int*)d_in[25];
    const int* pos_dst = (const int*)d_in[26];
    const int* neg_src = (const int*)d_in[27];
    const int* neg_dst = (const int*)d_in[28];

    float* ws   = (float*)d_ws;
    float* outp = (float*)d_out;
    int*   wi   = (int*)(ws + INT_OFF);
    unsigned short* xsb  = (unsigned short*)(ws + XSB_OFF);
    unsigned short* outb = (unsigned short*)(ws + OUTB_OFF);
    unsigned short* qbf  = (unsigned short*)(ws + QBF_OFF);
    unsigned short* kvb  = (unsigned short*)(ws + KV_OFF);
    unsigned short* zbb  = (unsigned short*)(ws + ZB_OFF);
    unsigned short* wtb  = (unsigned short*)(ws + WTB_OFF);
    float*          wfb  = ws + WFB_OFF;

    // zero degree + cursor counters (memset-clean lines keep atomics fast)
    hipMemsetAsync(wi + DEG_I, 0, 1200000L * sizeof(int), stream);

    // stage 1: lin GEMM + weight prep + CSR degree count (one launch)
    lin_prep_count<<<7913 + 9375, 256, 0, stream>>>(
        xq, xa, xk, lin_w, lin_b, xsb,
        q_w, a_w, k_w, k_b, v_w, v_b, a_rel, m_rel, wtb, wfb,
        edst[0], edst[1], edst[2], edst[3], wi + DEG_I);

    // CSR offsets
    const int nb = (NSEG + 1023) / 1024;   // 586
    scan1<<<nb, 256, 0, stream>>>(wi + DEG_I, wi + OFFS_I, wi + PART_I, NSEG);
    scan2<<<1, 256, 0, stream>>>(wi + PART_I, nb);
    scan3<<<(NSEG + 255) / 256, 256, 0, stream>>>(wi + OFFS_I, wi + PART_I, NSEG, ETOT);

    // stage 2: CSR fill (latency-bound) + q/kv GEMMs (compute) in one dispatch
    fill_qkv<<<13286, 256, 0, stream>>>(
        esrc[0], edst[0], esrc[1], edst[1], esrc[2], edst[2], esrc[3], edst[3],
        wi + OFFS_I, wi + CUR_I, wi + CSRC_I,
        xsb, wtb, q_b, wfb, qbf, kvb);

    // merged attention: one 16-lane group per destination node
    const float scale = 0.17677669529663687f;   // 1/sqrt(32)
    attn_all<<<31250, 256, 0, stream>>>(wi + OFFS_I, wi + CSRC_I, qbf, kvb,
                                        p_rel, scale, outb);

    // output head (+ bf16 z copies for pred)
    head_mfma<<<3908, 256, 0, stream>>>(outb, xsb, wtb, a_b, skip, outp, zbb);

    // link predictions
    pred_all<<<(200000 * 8 + 255) / 256, 256, 0, stream>>>(
        pos_src, pos_dst, neg_src, neg_dst, zbb, outp);
}

// Round 15
// 619.265 us; speedup vs baseline: 1.0257x; 1.0257x over previous
//
#include <hip/hip_runtime.h>
#include <math.h>

namespace {

constexpr int NQn = 100000, NAn = 200000, NKn = 200000;
constexpr int EPc = 100000, ENc = 100000;
constexpr int ETOT = 2400000, NSEG = 600000;

// ---- workspace layout (float element offsets) ----
constexpr long XSB_OFF  = 0;            // 16M floats = 32M bf16 xs
constexpr long OUTB_OFF = 16000000;     // 16M floats = 32M bf16 attn out
constexpr long QBF_OFF  = 32000000;     // 16M floats = 32M bf16 q
constexpr long KV_OFF   = 48000000;     // 38.4M floats = 600064 x 128 bf16
constexpr long ZB_OFF   = 86500000;     // 9.6M floats = 300000 x 64 bf16 (zq|za)
constexpr long WTB_OFF  = 96200000;     // bf16 transposed weights
constexpr long WFB_OFF  = 96250000;     // fp32 fused kv bias (512)
constexpr long INT_OFF  = 96300000;     // int region
// int offsets within (int*)(ws + INT_OFF):
constexpr long DEG_I  = 0;
constexpr long CUR_I  = 600000;
constexpr long OFFS_I = 1200000;
constexpr long PART_I = 1800064;
constexpr long CSRC_I = 1801088;

// wtb ushort offsets
constexpr int LINT_U = 0;        // 3 x 64 x 128
constexpr int QT_U   = 24576;    // 3 x 64 x 64
constexpr int AT_U   = 36864;    // 3 x 64 x 64
constexpr int WFT_U  = 49152;    // 4 x 128 x 64

__constant__ long c_rbase[4] = {0, 200000, 300032, 400064};

typedef __attribute__((ext_vector_type(8))) short bf16x8;
typedef __attribute__((ext_vector_type(4))) float f32x4;

__device__ inline f32x4 mfma16(bf16x8 a, bf16x8 b, f32x4 c) {
    return __builtin_amdgcn_mfma_f32_16x16x32_bf16(a, b, c, 0, 0, 0);
}

__device__ inline float gelu_f(float x) {
    return 0.5f * x * (1.0f + erff(x * 0.7071067811865475f));
}
__device__ inline float bf2f(unsigned short u) {
    return __uint_as_float(((unsigned)u) << 16);
}
__device__ inline unsigned short f2bf(float f) {
    unsigned u = __float_as_uint(f);
    return (unsigned short)((u + 0x7fffu + ((u >> 16) & 1u)) >> 16);
}

// block -> node-type mapping, 128-row tiles: counts {782, 1563, 1563}
__device__ inline void type_of_block128(int b, int& t, int& n0) {
    if (b < 782)       { t = 0; n0 = b * 128; }
    else if (b < 2345) { t = 1; n0 = (b - 782) * 128; }
    else               { t = 2; n0 = (b - 2345) * 128; }
}
// block -> node-type mapping, 64-row tiles: counts {1563, 3125, 3125}
__device__ inline void type_of_block64(int b, int& t, int& n0) {
    if (b < 1563)      { t = 0; n0 = b * 64; }
    else if (b < 4688) { t = 1; n0 = (b - 1563) * 64; }
    else               { t = 2; n0 = (b - 4688) * 64; }
}

// ---- staging helpers (XOR-swizzled LDS, 16B chunks) ----
template<int K>
__device__ inline void stage_bf16(unsigned short* lds, const unsigned short* src,
                                  int n0, int n, int tid)
{
    constexpr int CPR = K / 8;
    for (int c = tid; c < 128 * CPR; c += 256) {
        int row = c / CPR, kc = c % CPR;
        int node = n0 + row; if (node > n - 1) node = n - 1;
        uint4 v = *(const uint4*)&src[(long)node * K + kc * 8];
        int byte = (row * K + kc * 8) * 2;
        *(uint4*)((char*)lds + (byte ^ ((row & 7) << 4))) = v;
    }
}

// bf16 input + gelu applied during staging (K=64)
__device__ inline void stage_out_gelu(unsigned short* lds, const unsigned short* src,
                                      int n0, int n, int tid)
{
    for (int c = tid; c < 128 * 8; c += 256) {
        int row = c >> 3, kc = c & 7;
        int node = n0 + row; if (node > n - 1) node = n - 1;
        uint4 v = *(const uint4*)&src[(long)node * 64 + kc * 8];
        float f0 = gelu_f(bf2f((unsigned short)(v.x & 0xffffu)));
        float f1 = gelu_f(bf2f((unsigned short)(v.x >> 16)));
        float f2 = gelu_f(bf2f((unsigned short)(v.y & 0xffffu)));
        float f3 = gelu_f(bf2f((unsigned short)(v.y >> 16)));
        float f4 = gelu_f(bf2f((unsigned short)(v.z & 0xffffu)));
        float f5 = gelu_f(bf2f((unsigned short)(v.z >> 16)));
        float f6 = gelu_f(bf2f((unsigned short)(v.w & 0xffffu)));
        float f7 = gelu_f(bf2f((unsigned short)(v.w >> 16)));
        uint4 o;
        o.x = (unsigned)f2bf(f0) | ((unsigned)f2bf(f1) << 16);
        o.y = (unsigned)f2bf(f2) | ((unsigned)f2bf(f3) << 16);
        o.z = (unsigned)f2bf(f4) | ((unsigned)f2bf(f5) << 16);
        o.w = (unsigned)f2bf(f6) | ((unsigned)f2bf(f7) << 16);
        int byte = (row * 64 + kc * 8) * 2;
        *(uint4*)((char*)lds + (byte ^ ((row & 7) << 4))) = o;
    }
}

template<int K, int ROWS>
__device__ inline void stage_f32(unsigned short* lds, const float* src,
                                 int n0, int n, int tid)
{
    constexpr int CPR = K / 8;
    for (int c = tid; c < ROWS * CPR; c += 256) {
        int row = c / CPR, kc = c % CPR;
        int node = n0 + row; if (node > n - 1) node = n - 1;
        const float* sp = &src[(long)node * K + kc * 8];
        float4 f0 = *(const float4*)sp, f1 = *(const float4*)(sp + 4);
        uint4 v;
        v.x = (unsigned)f2bf(f0.x) | ((unsigned)f2bf(f0.y) << 16);
        v.y = (unsigned)f2bf(f0.z) | ((unsigned)f2bf(f0.w) << 16);
        v.z = (unsigned)f2bf(f1.x) | ((unsigned)f2bf(f1.y) << 16);
        v.w = (unsigned)f2bf(f1.z) | ((unsigned)f2bf(f1.w) << 16);
        int byte = (row * K + kc * 8) * 2;
        *(uint4*)((char*)lds + (byte ^ ((row & 7) << 4))) = v;
    }
}

template<int N, int K>
__device__ inline void stage_w(unsigned short* lds, const unsigned short* wt, int tid)
{
    constexpr int CPR = K / 8;
    for (int c = tid; c < N * CPR; c += 256) {
        int nr = c / CPR, kc = c % CPR;
        uint4 v = *(const uint4*)&wt[nr * K + kc * 8];
        int byte = (nr * K + kc * 8) * 2;
        *(uint4*)((char*)lds + (byte ^ ((nr & 7) << 4))) = v;
    }
}

// ---- MFMA core (TRANSPOSED operand order): wave w covers rows
// [w*16*MF, w*16*MF + 16*MF). acc[mf][nf]: col(lane&15)=node,
// rows=(lane>>4)*4+i = 4 consecutive out cols.
template<int K, int NF, int MF>
__device__ inline void mfma_coreT(const unsigned short* ldsX, const unsigned short* ldsW,
                                  f32x4 (&acc)[MF][NF], int lane, int w)
{
    const int lrow = lane & 15, lk = (lane >> 4) * 8;
    #pragma unroll
    for (int ks = 0; ks < K / 32; ++ks) {
        bf16x8 a[MF], b[NF];
        #pragma unroll
        for (int mf = 0; mf < MF; ++mf) {
            int row = w * (16 * MF) + mf * 16 + lrow;
            int byte = (row * K + ks * 32 + lk) * 2;
            a[mf] = *(const bf16x8*)((const char*)ldsX + (byte ^ ((row & 7) << 4)));
        }
        #pragma unroll
        for (int nf = 0; nf < NF; ++nf) {
            int nr = nf * 16 + lrow;
            int byte = (nr * K + ks * 32 + lk) * 2;
            b[nf] = *(const bf16x8*)((const char*)ldsW + (byte ^ ((nr & 7) << 4)));
        }
        #pragma unroll
        for (int mf = 0; mf < MF; ++mf)
            #pragma unroll
            for (int nf = 0; nf < NF; ++nf)
                acc[mf][nf] = mfma16(b[nf], a[mf], acc[mf][nf]);   // swapped!
    }
}

// ---- merged: fused relation weights + transposes + CSR degree count ---------
// blocks [0,4): fused rel W; [4,196): transposes; [196, 196+9375): csr count
__global__ void prep_count(const float* __restrict__ lin_w, const float* __restrict__ q_w,
                           const float* __restrict__ a_w,
                           const float* __restrict__ kw, const float* __restrict__ kb,
                           const float* __restrict__ vw, const float* __restrict__ vb,
                           const float* __restrict__ a_rel, const float* __restrict__ m_rel,
                           unsigned short* __restrict__ wtb, float* __restrict__ wfb,
                           const int* __restrict__ d0, const int* __restrict__ d1,
                           const int* __restrict__ d2, const int* __restrict__ d3,
                           int* __restrict__ deg)
{
    const int tid = threadIdx.x;
    if (blockIdx.x < 4) {
        const int r = blockIdx.x;
        const int st_tab[4] = {2, 0, 0, 1};
        const int st = st_tab[r];
        for (int idx = tid; idx < 8192; idx += 256) {
            int d = idx >> 7, c = idx & 127;
            int i = c >> 1, which = c & 1;
            int h = i >> 5, e = i & 31;
            const float* w   = (which ? vw : kw) + st * 4096;
            const float* rel = (which ? m_rel : a_rel) + r * 2048;
            float s = 0.f;
            #pragma unroll
            for (int c32 = 0; c32 < 32; ++c32)
                s += w[d * 64 + h * 32 + c32] * rel[h * 1024 + c32 * 32 + e];
            wtb[WFT_U + r * 8192 + c * 64 + d] = f2bf(s);
        }
        for (int idx = tid; idx < 128; idx += 256) {
            int i = idx >> 1, which = idx & 1;
            int h = i >> 5, e = i & 31;
            const float* b   = (which ? vb : kb) + st * 64;
            const float* rel = (which ? m_rel : a_rel) + r * 2048;
            float s = 0.f;
            #pragma unroll
            for (int c32 = 0; c32 < 32; ++c32)
                s += b[h * 32 + c32] * rel[h * 1024 + c32 * 32 + e];
            wfb[r * 128 + idx] = s;
        }
    } else if (blockIdx.x < 196) {
        int i = (blockIdx.x - 4) * 256 + tid;
        if (i < 24576) {
            int t = i / 8192, rem = i % 8192, nn = rem >> 7, kk = rem & 127;
            wtb[LINT_U + i] = f2bf(lin_w[t * 8192 + kk * 64 + nn]);
        } else if (i < 36864) {
            int j = i - 24576;
            int t = j / 4096, rem = j % 4096, nn = rem >> 6, kk = rem & 63;
            wtb[QT_U + j] = f2bf(q_w[t * 4096 + kk * 64 + nn]);
        } else if (i < 49152) {
            int j = i - 36864;
            int t = j / 4096, rem = j % 4096, nn = rem >> 6, kk = rem & 63;
            wtb[AT_U + j] = f2bf(a_w[t * 4096 + kk * 64 + nn]);
        }
    } else {
        int gid = (blockIdx.x - 196) * 256 + tid;
        if (gid < 800000)       atomicAdd(&deg[d0[gid]], 1);
        else if (gid < 1600000) atomicAdd(&deg[100000 + d1[gid - 800000]], 1);
        else if (gid < 2000000) atomicAdd(&deg[300000 + d2[gid - 1600000]], 1);
        else if (gid < 2400000) atomicAdd(&deg[500000 + d3[gid - 2000000]], 1);
    }
}

// ---- edge id -> (segment, source) mapping -----------------------------------
__device__ inline void edge_map(int gid,
                                const int* __restrict__ s0, const int* __restrict__ d0,
                                const int* __restrict__ s1, const int* __restrict__ d1,
                                const int* __restrict__ s2, const int* __restrict__ d2,
                                const int* __restrict__ s3, const int* __restrict__ d3,
                                int& seg, int& s)
{
    if (gid < 800000)       { seg = d0[gid];                    s = s0[gid]; }
    else if (gid < 1600000) { seg = 100000 + d1[gid - 800000];  s = s1[gid - 800000]; }
    else if (gid < 2000000) { seg = 300000 + d2[gid - 1600000]; s = s2[gid - 1600000]; }
    else                    { seg = 500000 + d3[gid - 2000000]; s = s3[gid - 2000000]; }
}

// ---- fused: CSR fill (latency-bound scatter, 4-edge ILP) + lin GEMM ----------
// 10157 blocks. b<4688: even -> lin tile b/2, odd -> fill block b/2.
// b>=4688: lin tile 2344 + (b-4688). Fill blocks: 2344 x 256 thr x 4 edges.
__global__ void __launch_bounds__(256)
fill_lin(const int* __restrict__ s0, const int* __restrict__ d0,
         const int* __restrict__ s1, const int* __restrict__ d1,
         const int* __restrict__ s2, const int* __restrict__ d2,
         const int* __restrict__ s3, const int* __restrict__ d3,
         const int* __restrict__ off, int* __restrict__ cur, int* __restrict__ csrc,
         const float* __restrict__ xq, const float* __restrict__ xa,
         const float* __restrict__ xk, const unsigned short* __restrict__ wtb,
         const float* __restrict__ lin_b, unsigned short* __restrict__ xsb)
{
    __shared__ unsigned short ldsX[64 * 128];   // 16 KB
    __shared__ unsigned short ldsW[64 * 128];   // 16 KB
    const int b = blockIdx.x;
    const int tid = threadIdx.x;

    int linb, fillb;
    if (b < 4688) {
        if (b & 1) { fillb = b >> 1; linb = -1; }
        else       { linb = b >> 1;  fillb = -1; }
    } else { linb = 2344 + (b - 4688); fillb = -1; }

    if (fillb >= 0) {
        // ---- CSR fill: 4 independent edges per thread (MLP on atomic+scatter)
        int base = fillb * 256 + tid;
        if (base < 600000) {
            int seg0, sv0, seg1, sv1, seg2, sv2, seg3, sv3;
            edge_map(base,           s0, d0, s1, d1, s2, d2, s3, d3, seg0, sv0);
            edge_map(base +  600000, s0, d0, s1, d1, s2, d2, s3, d3, seg1, sv1);
            edge_map(base + 1200000, s0, d0, s1, d1, s2, d2, s3, d3, seg2, sv2);
            edge_map(base + 1800000, s0, d0, s1, d1, s2, d2, s3, d3, seg3, sv3);
            int o0 = off[seg0], o1 = off[seg1], o2 = off[seg2], o3 = off[seg3];
            int slot0 = o0 + atomicAdd(&cur[seg0], 1);
            int slot1 = o1 + atomicAdd(&cur[seg1], 1);
            int slot2 = o2 + atomicAdd(&cur[seg2], 1);
            int slot3 = o3 + atomicAdd(&cur[seg3], 1);
            csrc[slot0] = sv0;
            csrc[slot1] = sv1;
            csrc[slot2] = sv2;
            csrc[slot3] = sv3;
        }
        return;
    }

    // ---- lin: xs_bf16 = relu(x @ lin_w + lin_b), 64-row tile
    int t, n0; type_of_block64(linb, t, n0);
    const int cnt[3] = {NQn, NAn, NKn};
    const long noff[3] = {0, NQn, NQn + NAn};
    const float* X = (t == 0) ? xq : (t == 1) ? xa : xk;
    const int n = cnt[t];

    stage_w<64, 128>(ldsW, wtb + LINT_U + t * 8192, tid);
    stage_f32<128, 64>(ldsX, X, n0, n, tid);
    __syncthreads();

    const int w = tid >> 6, lane = tid & 63;
    f32x4 acc[1][4] = {};
    mfma_coreT<128, 4, 1>(ldsX, ldsW, acc, lane, w);

    const int nodeL = lane & 15, colG = (lane >> 4) * 4;
    int node = n0 + w * 16 + nodeL;
    if (node < n) {
        #pragma unroll
        for (int nf = 0; nf < 4; ++nf) {
            int col0 = nf * 16 + colG;
            float4 bv = *(const float4*)&lin_b[t * 64 + col0];
            ushort4 o;
            o.x = f2bf(fmaxf(acc[0][nf][0] + bv.x, 0.f));
            o.y = f2bf(fmaxf(acc[0][nf][1] + bv.y, 0.f));
            o.z = f2bf(fmaxf(acc[0][nf][2] + bv.z, 0.f));
            o.w = f2bf(fmaxf(acc[0][nf][3] + bv.w, 0.f));
            *(ushort4*)&xsb[(noff[t] + node) * 64 + col0] = o;
        }
    }
}

// ---- qkv split: ONE (product, tile) per block -------------------------------
__global__ void __launch_bounds__(256)
qkv_split(const unsigned short* __restrict__ xsb, const unsigned short* __restrict__ wtb,
          const float* __restrict__ q_b, const float* __restrict__ wfb,
          unsigned short* __restrict__ qbf, unsigned short* __restrict__ kvb)
{
    __shared__ unsigned short ldsX[128 * 64];   // 16 KB
    __shared__ unsigned short ldsW[128 * 64];   // 16 KB
    const int cnt[3] = {NQn, NAn, NKn};
    const long noff[3] = {0, NQn, NQn + NAn};
    const int tid = threadIdx.x;
    const int w = tid >> 6, lane = tid & 63;
    const int nodeL = lane & 15, colG = (lane >> 4) * 4;
    const int b = blockIdx.x;

    if (b < 3908) {
        // ---- q product ----
        int t, n0; type_of_block128(b, t, n0);
        const int n = cnt[t];
        stage_bf16<64>(ldsX, xsb + noff[t] * 64, n0, n, tid);
        stage_w<64, 64>(ldsW, wtb + QT_U + t * 4096, tid);
        __syncthreads();

        f32x4 acc[2][4] = {};
        mfma_coreT<64, 4, 2>(ldsX, ldsW, acc, lane, w);
        #pragma unroll
        for (int mf = 0; mf < 2; ++mf) {
            int node = n0 + w * 32 + mf * 16 + nodeL;
            if (node < n) {
                #pragma unroll
                for (int nf = 0; nf < 4; ++nf) {
                    int col0 = nf * 16 + colG;
                    float4 bv = *(const float4*)&q_b[t * 64 + col0];
                    ushort4 o;
                    o.x = f2bf(acc[mf][nf][0] + bv.x);
                    o.y = f2bf(acc[mf][nf][1] + bv.y);
                    o.z = f2bf(acc[mf][nf][2] + bv.z);
                    o.w = f2bf(acc[mf][nf][3] + bv.w);
                    *(ushort4*)&qbf[(noff[t] + node) * 64 + col0] = o;
                }
            }
        }
    } else {
        // ---- kv product ----
        int kb = b - 3908, r, lb;
        if (kb < 1563)      { r = 0; lb = kb; }
        else if (kb < 2345) { r = 1; lb = kb - 1563; }
        else if (kb < 3127) { r = 2; lb = kb - 2345; }
        else                { r = 3; lb = kb - 3127; }
        const int stt[4] = {2, 0, 0, 1};
        const int st = stt[r];
        const int n0 = lb * 128;
        const int n = cnt[st];
        const long rb = c_rbase[r];

        stage_bf16<64>(ldsX, xsb + noff[st] * 64, n0, n, tid);
        stage_w<128, 64>(ldsW, wtb + WFT_U + r * 8192, tid);
        __syncthreads();

        f32x4 acc[2][8] = {};
        mfma_coreT<64, 8, 2>(ldsX, ldsW, acc, lane, w);
        #pragma unroll
        for (int mf = 0; mf < 2; ++mf) {
            int node = n0 + w * 32 + mf * 16 + nodeL;
            if (node < n) {
                #pragma unroll
                for (int nf = 0; nf < 8; ++nf) {
                    int col0 = nf * 16 + colG;
                    float4 bv = *(const float4*)&wfb[r * 128 + col0];
                    ushort4 o;
                    o.x = f2bf(acc[mf][nf][0] + bv.x);
                    o.y = f2bf(acc[mf][nf][1] + bv.y);
                    o.z = f2bf(acc[mf][nf][2] + bv.z);
                    o.w = f2bf(acc[mf][nf][3] + bv.w);
                    *(ushort4*)&kvb[(rb + node) * 128 + col0] = o;
                }
            }
        }
    }
}

// ---- head: z = beta*(gelu(out) @ a_w + a_b) + (1-beta)*xs; bf16 z copies for pred
__global__ void __launch_bounds__(256)
head_mfma(const unsigned short* __restrict__ outb, const unsigned short* __restrict__ xsb,
          const unsigned short* __restrict__ wtb, const float* __restrict__ a_b,
          const float* __restrict__ skip, float* __restrict__ z,
          unsigned short* __restrict__ zb)
{
    __shared__ unsigned short ldsX[128 * 64];
    __shared__ unsigned short ldsW[64 * 64];
    int t, n0; type_of_block128(blockIdx.x, t, n0);
    const int cnt[3] = {NQn, NAn, NKn};
    const long noff[3] = {0, NQn, NQn + NAn};
    const long zoff[3] = {200000L, 6600000L, 19400000L};
    const int n = cnt[t];
    const int tid = threadIdx.x;

    stage_w<64, 64>(ldsW, wtb + AT_U + t * 4096, tid);
    stage_out_gelu(ldsX, outb + noff[t] * 64, n0, n, tid);
    __syncthreads();

    const int w = tid >> 6, lane = tid & 63;
    f32x4 acc[2][4] = {};
    mfma_coreT<64, 4, 2>(ldsX, ldsW, acc, lane, w);

    const float beta = 1.f / (1.f + expf(-skip[t]));
    const int nodeL = lane & 15, colG = (lane >> 4) * 4;
    #pragma unroll
    for (int mf = 0; mf < 2; ++mf) {
        int node = n0 + w * 32 + mf * 16 + nodeL;
        if (node < n) {
            #pragma unroll
            for (int nf = 0; nf < 4; ++nf) {
                int col0 = nf * 16 + colG;
                float4 bv = *(const float4*)&a_b[t * 64 + col0];
                ushort4 rv = *(const ushort4*)&xsb[(noff[t] + node) * 64 + col0];
                float4 o;
                o.x = beta * (acc[mf][nf][0] + bv.x) + (1.f - beta) * bf2f(rv.x);
                o.y = beta * (acc[mf][nf][1] + bv.y) + (1.f - beta) * bf2f(rv.y);
                o.z = beta * (acc[mf][nf][2] + bv.z) + (1.f - beta) * bf2f(rv.z);
                o.w = beta * (acc[mf][nf][3] + bv.w) + (1.f - beta) * bf2f(rv.w);
                *(float4*)&z[zoff[t] + (long)node * 64 + col0] = o;
                if (t < 2) {
                    ushort4 p;
                    p.x = f2bf(o.x); p.y = f2bf(o.y); p.z = f2bf(o.z); p.w = f2bf(o.w);
                    long zrow = (t == 0) ? (long)node : 100000L + node;
                    *(ushort4*)&zb[zrow * 64 + col0] = p;
                }
            }
        }
    }
}

// ---- scans -------------------------------------------------------------------
__global__ void scan1(const int* __restrict__ in, int* __restrict__ out,
                      int* __restrict__ part, int n)
{
    __shared__ int lds[256];
    const int tid = threadIdx.x;
    const int base = blockIdx.x * 1024 + tid * 4;
    int v[4];
    #pragma unroll
    for (int k = 0; k < 4; ++k) v[k] = (base + k < n) ? in[base + k] : 0;
    int tsum = v[0] + v[1] + v[2] + v[3];
    lds[tid] = tsum;
    __syncthreads();
    for (int off = 1; off < 256; off <<= 1) {
        int t = (tid >= off) ? lds[tid - off] : 0;
        __syncthreads();
        lds[tid] += t;
        __syncthreads();
    }
    int excl = lds[tid] - tsum;
    #pragma unroll
    for (int k = 0; k < 4; ++k) {
        if (base + k < n) out[base + k] = excl;
        excl += v[k];
    }
    if (tid == 255) part[blockIdx.x] = lds[255];
}

__global__ void scan2(int* __restrict__ part, int nb)   // nb <= 1024
{
    __shared__ int lds[256];
    const int tid = threadIdx.x;
    const int base = tid * 4;
    int v[4];
    #pragma unroll
    for (int k = 0; k < 4; ++k) v[k] = (base + k < nb) ? part[base + k] : 0;
    int tsum = v[0] + v[1] + v[2] + v[3];
    lds[tid] = tsum;
    __syncthreads();
    for (int off = 1; off < 256; off <<= 1) {
        int t = (tid >= off) ? lds[tid - off] : 0;
        __syncthreads();
        lds[tid] += t;
        __syncthreads();
    }
    int excl = lds[tid] - tsum;
    #pragma unroll
    for (int k = 0; k < 4; ++k) {
        if (base + k < nb) part[base + k] = excl;
        excl += v[k];
    }
}

__global__ void scan3(int* __restrict__ off, const int* __restrict__ part, int n, int E)
{
    int i = blockIdx.x * 256 + threadIdx.x;
    if (i < n) off[i] += part[i >> 10];
    if (i == 0) off[n] = E;
}

// ---- fused attention: one 16-lane group per destination node ----------------
// No max-tracking (shift-invariant softmax; alphas O(1), clamped at 115 in exp2
// domain). p_rel*scale*log2e folded into q. 4-edge ILP per iteration.
__device__ inline void attn_node(const int* __restrict__ csrc, int begin, int end,
                                 const unsigned short* __restrict__ kvt,
                                 const float qv[4], int j, float res[4])
{
    float ss = 0.f, a0 = 0.f, a1 = 0.f, a2 = 0.f, a3 = 0.f;

    for (int t = begin; t < end; t += 4) {
        bool v1 = (t + 1 < end), v2 = (t + 2 < end), v3 = (t + 3 < end);
        int s0 = csrc[t];
        int s1 = csrc[v1 ? t + 1 : t];
        int s2 = csrc[v2 ? t + 2 : t];
        int s3 = csrc[v3 ? t + 3 : t];
        uint4 k0 = *(const uint4*)(kvt + (long)s0 * 128 + j * 8);
        uint4 k1 = *(const uint4*)(kvt + (long)s1 * 128 + j * 8);
        uint4 k2 = *(const uint4*)(kvt + (long)s2 * 128 + j * 8);
        uint4 k3 = *(const uint4*)(kvt + (long)s3 * 128 + j * 8);

        float p0 = __uint_as_float(k0.x << 16) * qv[0] + __uint_as_float(k0.y << 16) * qv[1]
                 + __uint_as_float(k0.z << 16) * qv[2] + __uint_as_float(k0.w << 16) * qv[3];
        float p1 = __uint_as_float(k1.x << 16) * qv[0] + __uint_as_float(k1.y << 16) * qv[1]
                 + __uint_as_float(k1.z << 16) * qv[2] + __uint_as_float(k1.w << 16) * qv[3];
        float p2 = __uint_as_float(k2.x << 16) * qv[0] + __uint_as_float(k2.y << 16) * qv[1]
                 + __uint_as_float(k2.z << 16) * qv[2] + __uint_as_float(k2.w << 16) * qv[3];
        float p3 = __uint_as_float(k3.x << 16) * qv[0] + __uint_as_float(k3.y << 16) * qv[1]
                 + __uint_as_float(k3.z << 16) * qv[2] + __uint_as_float(k3.w << 16) * qv[3];

        p0 += __shfl_xor(p0, 1);  p1 += __shfl_xor(p1, 1);
        p2 += __shfl_xor(p2, 1);  p3 += __shfl_xor(p3, 1);
        p0 += __shfl_xor(p0, 2);  p1 += __shfl_xor(p1, 2);
        p2 += __shfl_xor(p2, 2);  p3 += __shfl_xor(p3, 2);
        p0 += __shfl_xor(p0, 4);  p1 += __shfl_xor(p1, 4);
        p2 += __shfl_xor(p2, 4);  p3 += __shfl_xor(p3, 4);

        float w0 = exp2f(fminf(p0, 115.f));
        float w1 = v1 ? exp2f(fminf(p1, 115.f)) : 0.f;
        float w2 = v2 ? exp2f(fminf(p2, 115.f)) : 0.f;
        float w3 = v3 ? exp2f(fminf(p3, 115.f)) : 0.f;

        ss += (w0 + w1) + (w2 + w3);
        a0 += w0 * __uint_as_float(k0.x & 0xffff0000u) + w1 * __uint_as_float(k1.x & 0xffff0000u)
            + w2 * __uint_as_float(k2.x & 0xffff0000u) + w3 * __uint_as_float(k3.x & 0xffff0000u);
        a1 += w0 * __uint_as_float(k0.y & 0xffff0000u) + w1 * __uint_as_float(k1.y & 0xffff0000u)
            + w2 * __uint_as_float(k2.y & 0xffff0000u) + w3 * __uint_as_float(k3.y & 0xffff0000u);
        a2 += w0 * __uint_as_float(k0.z & 0xffff0000u) + w1 * __uint_as_float(k1.z & 0xffff0000u)
            + w2 * __uint_as_float(k2.z & 0xffff0000u) + w3 * __uint_as_float(k3.z & 0xffff0000u);
        a3 += w0 * __uint_as_float(k0.w & 0xffff0000u) + w1 * __uint_as_float(k1.w & 0xffff0000u)
            + w2 * __uint_as_float(k2.w & 0xffff0000u) + w3 * __uint_as_float(k3.w & 0xffff0000u);
    }

    float inv = 1.f / (ss + 1e-16f);
    res[0] = a0 * inv; res[1] = a1 * inv; res[2] = a2 * inv; res[3] = a3 * inv;
}

__global__ void __launch_bounds__(256)
attn_all(const int* __restrict__ off, const int* __restrict__ csrc,
         const unsigned short* __restrict__ qbf, const unsigned short* __restrict__ kv,
         const float* __restrict__ prel, float scale, unsigned short* __restrict__ outb)
{
    const int tid = threadIdx.x;
    const int nid = blockIdx.x * 16 + (tid >> 4);   // 16 nodes per block
    const int j = tid & 15;
    const int h = j >> 3;
    const float l2e = 1.4426950408889634f;

    long row; int segA, segB = -1; long kbA, kbB = 0; float psA, psB = 0.f;
    if (nid < 100000) {
        row = nid;
        segA = nid;            kbA = c_rbase[0]; psA = prel[0 + h] * scale * l2e;
        segB = 500000 + nid;   kbB = c_rbase[3]; psB = prel[6 + h] * scale * l2e;
    } else if (nid < 300000) {
        int kk = nid - 100000;
        row = 300000 + kk;
        segA = 100000 + kk;    kbA = c_rbase[1]; psA = prel[2 + h] * scale * l2e;
    } else {
        int aa = nid - 300000;
        row = 100000 + aa;
        segA = 300000 + aa;    kbA = c_rbase[2]; psA = prel[4 + h] * scale * l2e;
    }

    ushort4 q4 = *(const ushort4*)&qbf[row * 64 + 4 * j];
    float qraw[4] = {bf2f(q4.x), bf2f(q4.y), bf2f(q4.z), bf2f(q4.w)};

    float res[4];
    {
        float qv[4] = {qraw[0] * psA, qraw[1] * psA, qraw[2] * psA, qraw[3] * psA};
        attn_node(csrc, off[segA], off[segA + 1], kv + kbA * 128, qv, j, res);
    }
    if (segB >= 0) {
        float qv[4] = {qraw[0] * psB, qraw[1] * psB, qraw[2] * psB, qraw[3] * psB};
        float r2[4];
        attn_node(csrc, off[segB], off[segB + 1], kv + kbB * 128, qv, j, r2);
        res[0] += r2[0]; res[1] += r2[1]; res[2] += r2[2]; res[3] += r2[3];
    }

    ushort4 o;
    o.x = f2bf(res[0]); o.y = f2bf(res[1]); o.z = f2bf(res[2]); o.w = f2bf(res[3]);
    *(ushort4*)&outb[row * 64 + 4 * j] = o;
}

// ---- link prediction (bf16 z gathers) ---------------------------------------
__global__ void pred_all(const int* __restrict__ psrc, const int* __restrict__ pdst,
                         const int* __restrict__ nsrc, const int* __restrict__ ndst,
                         const unsigned short* __restrict__ zb, float* __restrict__ out)
{
    int t = blockIdx.x * 256 + threadIdx.x;
    int g = t >> 3, lane = t & 7;
    if (g >= EPc + ENc) return;
    int s, d;
    if (g < EPc) { s = psrc[g]; d = pdst[g]; }
    else         { int gg = g - EPc; s = nsrc[gg]; d = ndst[gg]; }
    uint4 zs = *(const uint4*)&zb[(long)s * 64 + lane * 8];
    uint4 zd = *(const uint4*)&zb[(100000L + d) * 64 + lane * 8];
    float p = 0.f;
    p += bf2f((unsigned short)(zs.x & 0xffffu)) * bf2f((unsigned short)(zd.x & 0xffffu));
    p += bf2f((unsigned short)(zs.x >> 16))     * bf2f((unsigned short)(zd.x >> 16));
    p += bf2f((unsigned short)(zs.y & 0xffffu)) * bf2f((unsigned short)(zd.y & 0xffffu));
    p += bf2f((unsigned short)(zs.y >> 16))     * bf2f((unsigned short)(zd.y >> 16));
    p += bf2f((unsigned short)(zs.z & 0xffffu)) * bf2f((unsigned short)(zd.z & 0xffffu));
    p += bf2f((unsigned short)(zs.z >> 16))     * bf2f((unsigned short)(zd.z >> 16));
    p += bf2f((unsigned short)(zs.w & 0xffffu)) * bf2f((unsigned short)(zd.w & 0xffffu));
    p += bf2f((unsigned short)(zs.w >> 16))     * bf2f((unsigned short)(zd.w >> 16));
    p += __shfl_xor(p, 1);
    p += __shfl_xor(p, 2);
    p += __shfl_xor(p, 4);
    if (lane == 0) out[g] = 1.f / (1.f + expf(-p));
}

} // namespace

extern "C" void kernel_launch(void* const* d_in, const int* in_sizes, int n_in,
                              void* d_out, int out_size, void* d_ws, size_t ws_size,
                              hipStream_t stream)
{
    const float* xq    = (const float*)d_in[0];
    const float* xa    = (const float*)d_in[1];
    const float* xk    = (const float*)d_in[2];
    const float* lin_w = (const float*)d_in[3];
    const float* lin_b = (const float*)d_in[4];
    const float* k_w   = (const float*)d_in[5];
    const float* k_b   = (const float*)d_in[6];
    const float* q_w   = (const float*)d_in[7];
    const float* q_b   = (const float*)d_in[8];
    const float* v_w   = (const float*)d_in[9];
    const float* v_b   = (const float*)d_in[10];
    const float* a_w   = (const float*)d_in[11];
    const float* a_b   = (const float*)d_in[12];
    const float* a_rel = (const float*)d_in[13];
    const float* m_rel = (const float*)d_in[14];
    const float* p_rel = (const float*)d_in[15];
    const float* skip  = (const float*)d_in[16];
    const int* esrc[4] = {(const int*)d_in[17], (const int*)d_in[19], (const int*)d_in[21], (const int*)d_in[23]};
    const int* edst[4] = {(const int*)d_in[18], (const int*)d_in[20], (const int*)d_in[22], (const int*)d_in[24]};
    const int* pos_src = (const int*)d_in[25];
    const int* pos_dst = (const int*)d_in[26];
    const int* neg_src = (const int*)d_in[27];
    const int* neg_dst = (const int*)d_in[28];

    float* ws   = (float*)d_ws;
    float* outp = (float*)d_out;
    int*   wi   = (int*)(ws + INT_OFF);
    unsigned short* xsb  = (unsigned short*)(ws + XSB_OFF);
    unsigned short* outb = (unsigned short*)(ws + OUTB_OFF);
    unsigned short* qbf  = (unsigned short*)(ws + QBF_OFF);
    unsigned short* kvb  = (unsigned short*)(ws + KV_OFF);
    unsigned short* zbb  = (unsigned short*)(ws + ZB_OFF);
    unsigned short* wtb  = (unsigned short*)(ws + WTB_OFF);
    float*          wfb  = ws + WFB_OFF;

    // zero degree + cursor counters (memset-clean lines keep atomics fast)
    hipMemsetAsync(wi + DEG_I, 0, 1200000L * sizeof(int), stream);

    // merged: fused rel weights + transposes + CSR degree count (one launch)
    prep_count<<<196 + 9375, 256, 0, stream>>>(
        lin_w, q_w, a_w, k_w, k_b, v_w, v_b, a_rel, m_rel, wtb, wfb,
        edst[0], edst[1], edst[2], edst[3], wi + DEG_I);

    // CSR offsets
    const int nb = (NSEG + 1023) / 1024;   // 586
    scan1<<<nb, 256, 0, stream>>>(wi + DEG_I, wi + OFFS_I, wi + PART_I, NSEG);
    scan2<<<1, 256, 0, stream>>>(wi + PART_I, nb);
    scan3<<<(NSEG + 255) / 256, 256, 0, stream>>>(wi + OFFS_I, wi + PART_I, NSEG, ETOT);

    // fused: CSR fill (latency-bound, 4-edge ILP) + lin GEMM (BW-bound)
    fill_lin<<<10157, 256, 0, stream>>>(
        esrc[0], edst[0], esrc[1], edst[1], esrc[2], edst[2], esrc[3], edst[3],
        wi + OFFS_I, wi + CUR_I, wi + CSRC_I,
        xq, xa, xk, wtb, lin_b, xsb);

    // q + kv as one-block-per-product
    qkv_split<<<8598, 256, 0, stream>>>(xsb, wtb, q_b, wfb, qbf, kvb);

    // merged attention: one 16-lane group per destination node
    const float scale = 0.17677669529663687f;   // 1/sqrt(32)
    attn_all<<<31250, 256, 0, stream>>>(wi + OFFS_I, wi + CSRC_I, qbf, kvb,
                                        p_rel, scale, outb);

    // output head (+ bf16 z copies for pred)
    head_mfma<<<3908, 256, 0, stream>>>(outb, xsb, wtb, a_b, skip, outp, zbb);

    // link predictions
    pred_all<<<(200000 * 8 + 255) / 256, 256, 0, stream>>>(
        pos_src, pos_dst, neg_src, neg_dst, zbb, outp);
}

// Round 16
// 549.007 us; speedup vs baseline: 1.1570x; 1.1280x over previous
//
#include <hip/hip_runtime.h>
#include <math.h>

namespace {

constexpr int NQn = 100000, NAn = 200000, NKn = 200000;
constexpr int EPc = 100000, ENc = 100000;
constexpr int ETOT = 2400000, NSEG = 600000;
constexpr int LIN_THREADS = 7813 * 256;   // 2,000,128

// ---- workspace layout (float element offsets) ----
constexpr long XSB_OFF  = 0;            // 16M floats = 32M bf16 xs
constexpr long OUTB_OFF = 16000000;     // 16M floats = 32M bf16 attn out
constexpr long QBF_OFF  = 32000000;     // 16M floats = 32M bf16 q
constexpr long KV_OFF   = 48000000;     // 38.4M floats = 600064 x 128 bf16
constexpr long ZB_OFF   = 86500000;     // 9.6M floats = 300000 x 64 bf16 (zq|za)
constexpr long WTB_OFF  = 96200000;     // bf16 transposed weights
constexpr long WFB_OFF  = 96250000;     // fp32 fused kv bias (512)
constexpr long INT_OFF  = 96300000;     // int region
// int offsets within (int*)(ws + INT_OFF):
constexpr long DEG_I  = 0;          //   600,000
constexpr long OFFS_I = 600064;     //   600,064
constexpr long PART_I = 1200128;    //     1,024
constexpr long RANK_I = 1201152;    // 2,400,000
constexpr long CSRC_I = 3601152;    // 2,400,000

// wtb ushort offsets
constexpr int LINT_U = 0;        // 3 x 64 x 128
constexpr int QT_U   = 24576;    // 3 x 64 x 64
constexpr int AT_U   = 36864;    // 3 x 64 x 64
constexpr int WFT_U  = 49152;    // 4 x 128 x 64

__constant__ long c_rbase[4] = {0, 200000, 300032, 400064};

typedef __attribute__((ext_vector_type(8))) short bf16x8;
typedef __attribute__((ext_vector_type(4))) float f32x4;

__device__ inline f32x4 mfma16(bf16x8 a, bf16x8 b, f32x4 c) {
    return __builtin_amdgcn_mfma_f32_16x16x32_bf16(a, b, c, 0, 0, 0);
}

__device__ inline float gelu_f(float x) {
    return 0.5f * x * (1.0f + erff(x * 0.7071067811865475f));
}
__device__ inline float bf2f(unsigned short u) {
    return __uint_as_float(((unsigned)u) << 16);
}
__device__ inline unsigned short f2bf(float f) {
    unsigned u = __float_as_uint(f);
    return (unsigned short)((u + 0x7fffu + ((u >> 16) & 1u)) >> 16);
}

// block -> node-type mapping, 128-row tiles: counts {782, 1563, 1563}
__device__ inline void type_of_block128(int b, int& t, int& n0) {
    if (b < 782)       { t = 0; n0 = b * 128; }
    else if (b < 2345) { t = 1; n0 = (b - 782) * 128; }
    else               { t = 2; n0 = (b - 2345) * 128; }
}
// block -> node-type mapping, 64-row tiles: counts {1563, 3125, 3125}
__device__ inline void type_of_block64(int b, int& t, int& n0) {
    if (b < 1563)      { t = 0; n0 = b * 64; }
    else if (b < 4688) { t = 1; n0 = (b - 1563) * 64; }
    else               { t = 2; n0 = (b - 4688) * 64; }
}

// ---- staging helpers (XOR-swizzled LDS, 16B chunks) ----
template<int K>
__device__ inline void stage_bf16(unsigned short* lds, const unsigned short* src,
                                  int n0, int n, int tid)
{
    constexpr int CPR = K / 8;
    for (int c = tid; c < 128 * CPR; c += 256) {
        int row = c / CPR, kc = c % CPR;
        int node = n0 + row; if (node > n - 1) node = n - 1;
        uint4 v = *(const uint4*)&src[(long)node * K + kc * 8];
        int byte = (row * K + kc * 8) * 2;
        *(uint4*)((char*)lds + (byte ^ ((row & 7) << 4))) = v;
    }
}

// bf16 input + gelu applied during staging (K=64)
__device__ inline void stage_out_gelu(unsigned short* lds, const unsigned short* src,
                                      int n0, int n, int tid)
{
    for (int c = tid; c < 128 * 8; c += 256) {
        int row = c >> 3, kc = c & 7;
        int node = n0 + row; if (node > n - 1) node = n - 1;
        uint4 v = *(const uint4*)&src[(long)node * 64 + kc * 8];
        float f0 = gelu_f(bf2f((unsigned short)(v.x & 0xffffu)));
        float f1 = gelu_f(bf2f((unsigned short)(v.x >> 16)));
        float f2 = gelu_f(bf2f((unsigned short)(v.y & 0xffffu)));
        float f3 = gelu_f(bf2f((unsigned short)(v.y >> 16)));
        float f4 = gelu_f(bf2f((unsigned short)(v.z & 0xffffu)));
        float f5 = gelu_f(bf2f((unsigned short)(v.z >> 16)));
        float f6 = gelu_f(bf2f((unsigned short)(v.w & 0xffffu)));
        float f7 = gelu_f(bf2f((unsigned short)(v.w >> 16)));
        uint4 o;
        o.x = (unsigned)f2bf(f0) | ((unsigned)f2bf(f1) << 16);
        o.y = (unsigned)f2bf(f2) | ((unsigned)f2bf(f3) << 16);
        o.z = (unsigned)f2bf(f4) | ((unsigned)f2bf(f5) << 16);
        o.w = (unsigned)f2bf(f6) | ((unsigned)f2bf(f7) << 16);
        int byte = (row * 64 + kc * 8) * 2;
        *(uint4*)((char*)lds + (byte ^ ((row & 7) << 4))) = o;
    }
}

template<int K, int ROWS>
__device__ inline void stage_f32(unsigned short* lds, const float* src,
                                 int n0, int n, int tid)
{
    constexpr int CPR = K / 8;
    for (int c = tid; c < ROWS * CPR; c += 256) {
        int row = c / CPR, kc = c % CPR;
        int node = n0 + row; if (node > n - 1) node = n - 1;
        const float* sp = &src[(long)node * K + kc * 8];
        float4 f0 = *(const float4*)sp, f1 = *(const float4*)(sp + 4);
        uint4 v;
        v.x = (unsigned)f2bf(f0.x) | ((unsigned)f2bf(f0.y) << 16);
        v.y = (unsigned)f2bf(f0.z) | ((unsigned)f2bf(f0.w) << 16);
        v.z = (unsigned)f2bf(f1.x) | ((unsigned)f2bf(f1.y) << 16);
        v.w = (unsigned)f2bf(f1.z) | ((unsigned)f2bf(f1.w) << 16);
        int byte = (row * K + kc * 8) * 2;
        *(uint4*)((char*)lds + (byte ^ ((row & 7) << 4))) = v;
    }
}

template<int N, int K>
__device__ inline void stage_w(unsigned short* lds, const unsigned short* wt, int tid)
{
    constexpr int CPR = K / 8;
    for (int c = tid; c < N * CPR; c += 256) {
        int nr = c / CPR, kc = c % CPR;
        uint4 v = *(const uint4*)&wt[nr * K + kc * 8];
        int byte = (nr * K + kc * 8) * 2;
        *(uint4*)((char*)lds + (byte ^ ((nr & 7) << 4))) = v;
    }
}

// ---- MFMA core (TRANSPOSED operand order): wave w covers rows
// [w*16*MF, w*16*MF + 16*MF). acc[mf][nf]: col(lane&15)=node,
// rows=(lane>>4)*4+i = 4 consecutive out cols.
template<int K, int NF, int MF>
__device__ inline void mfma_coreT(const unsigned short* ldsX, const unsigned short* ldsW,
                                  f32x4 (&acc)[MF][NF], int lane, int w)
{
    const int lrow = lane & 15, lk = (lane >> 4) * 8;
    #pragma unroll
    for (int ks = 0; ks < K / 32; ++ks) {
        bf16x8 a[MF], b[NF];
        #pragma unroll
        for (int mf = 0; mf < MF; ++mf) {
            int row = w * (16 * MF) + mf * 16 + lrow;
            int byte = (row * K + ks * 32 + lk) * 2;
            a[mf] = *(const bf16x8*)((const char*)ldsX + (byte ^ ((row & 7) << 4)));
        }
        #pragma unroll
        for (int nf = 0; nf < NF; ++nf) {
            int nr = nf * 16 + lrow;
            int byte = (nr * K + ks * 32 + lk) * 2;
            b[nf] = *(const bf16x8*)((const char*)ldsW + (byte ^ ((nr & 7) << 4)));
        }
        #pragma unroll
        for (int mf = 0; mf < MF; ++mf)
            #pragma unroll
            for (int nf = 0; nf < NF; ++nf)
                acc[mf][nf] = mfma16(b[nf], a[mf], acc[mf][nf]);   // swapped!
    }
}

// ---- edge id -> segment (+source) mapping ------------------------------------
__device__ inline void edge_map(int gid,
                                const int* __restrict__ s0, const int* __restrict__ d0,
                                const int* __restrict__ s1, const int* __restrict__ d1,
                                const int* __restrict__ s2, const int* __restrict__ d2,
                                const int* __restrict__ s3, const int* __restrict__ d3,
                                int& seg, int& s)
{
    if (gid < 800000)       { seg = d0[gid];                    s = s0[gid]; }
    else if (gid < 1600000) { seg = 100000 + d1[gid - 800000];  s = s1[gid - 800000]; }
    else if (gid < 2000000) { seg = 300000 + d2[gid - 1600000]; s = s2[gid - 1600000]; }
    else                    { seg = 500000 + d3[gid - 2000000]; s = s3[gid - 2000000]; }
}
__device__ inline int edge_seg(int gid,
                               const int* __restrict__ d0, const int* __restrict__ d1,
                               const int* __restrict__ d2, const int* __restrict__ d3)
{
    if (gid < 800000)       return d0[gid];
    else if (gid < 1600000) return 100000 + d1[gid - 800000];
    else if (gid < 2000000) return 300000 + d2[gid - 1600000];
    else                    return 500000 + d3[gid - 2000000];
}

// ---- merged: fused relation weights + transposes + CSR count (stores rank) ---
// blocks [0,4): fused rel W; [4,196): transposes; [196, 196+9375): csr count
__global__ void prep_count(const float* __restrict__ lin_w, const float* __restrict__ q_w,
                           const float* __restrict__ a_w,
                           const float* __restrict__ kw, const float* __restrict__ kb,
                           const float* __restrict__ vw, const float* __restrict__ vb,
                           const float* __restrict__ a_rel, const float* __restrict__ m_rel,
                           unsigned short* __restrict__ wtb, float* __restrict__ wfb,
                           const int* __restrict__ d0, const int* __restrict__ d1,
                           const int* __restrict__ d2, const int* __restrict__ d3,
                           int* __restrict__ deg, int* __restrict__ rank)
{
    const int tid = threadIdx.x;
    if (blockIdx.x < 4) {
        const int r = blockIdx.x;
        const int st_tab[4] = {2, 0, 0, 1};
        const int st = st_tab[r];
        for (int idx = tid; idx < 8192; idx += 256) {
            int d = idx >> 7, c = idx & 127;
            int i = c >> 1, which = c & 1;
            int h = i >> 5, e = i & 31;
            const float* w   = (which ? vw : kw) + st * 4096;
            const float* rel = (which ? m_rel : a_rel) + r * 2048;
            float s = 0.f;
            #pragma unroll
            for (int c32 = 0; c32 < 32; ++c32)
                s += w[d * 64 + h * 32 + c32] * rel[h * 1024 + c32 * 32 + e];
            wtb[WFT_U + r * 8192 + c * 64 + d] = f2bf(s);
        }
        for (int idx = tid; idx < 128; idx += 256) {
            int i = idx >> 1, which = idx & 1;
            int h = i >> 5, e = i & 31;
            const float* b   = (which ? vb : kb) + st * 64;
            const float* rel = (which ? m_rel : a_rel) + r * 2048;
            float s = 0.f;
            #pragma unroll
            for (int c32 = 0; c32 < 32; ++c32)
                s += b[h * 32 + c32] * rel[h * 1024 + c32 * 32 + e];
            wfb[r * 128 + idx] = s;
        }
    } else if (blockIdx.x < 196) {
        int i = (blockIdx.x - 4) * 256 + tid;
        if (i < 24576) {
            int t = i / 8192, rem = i % 8192, nn = rem >> 7, kk = rem & 127;
            wtb[LINT_U + i] = f2bf(lin_w[t * 8192 + kk * 64 + nn]);
        } else if (i < 36864) {
            int j = i - 24576;
            int t = j / 4096, rem = j % 4096, nn = rem >> 6, kk = rem & 63;
            wtb[QT_U + j] = f2bf(q_w[t * 4096 + kk * 64 + nn]);
        } else if (i < 49152) {
            int j = i - 36864;
            int t = j / 4096, rem = j % 4096, nn = rem >> 6, kk = rem & 63;
            wtb[AT_U + j] = f2bf(a_w[t * 4096 + kk * 64 + nn]);
        }
    } else {
        int gid = (blockIdx.x - 196) * 256 + tid;
        if (gid < ETOT) {
            int seg = edge_seg(gid, d0, d1, d2, d3);
            rank[gid] = atomicAdd(&deg[seg], 1);
        }
    }
}

// ---- fused: lin GEMM + atomic-free CSR fill carried by every thread ----------
// 7813 blocks x 256 threads; thread gid handles edge gid (always) and
// edge gid+LIN_THREADS (first ETOT-LIN_THREADS threads).
__global__ void __launch_bounds__(256)
lin_fill(const int* __restrict__ s0, const int* __restrict__ d0,
         const int* __restrict__ s1, const int* __restrict__ d1,
         const int* __restrict__ s2, const int* __restrict__ d2,
         const int* __restrict__ s3, const int* __restrict__ d3,
         const int* __restrict__ off, const int* __restrict__ rank,
         int* __restrict__ csrc,
         const float* __restrict__ xq, const float* __restrict__ xa,
         const float* __restrict__ xk, const unsigned short* __restrict__ wtb,
         const float* __restrict__ lin_b, unsigned short* __restrict__ xsb)
{
    __shared__ unsigned short ldsX[64 * 128];   // 16 KB
    __shared__ unsigned short ldsW[64 * 128];   // 16 KB
    const int tid = threadIdx.x;
    const int gid = blockIdx.x * 256 + tid;

    // ---- fill: issue edge loads + scattered off gathers early
    int segA, sA;
    edge_map(gid, s0, d0, s1, d1, s2, d2, s3, d3, segA, sA);
    int rkA = rank[gid];
    int offA = off[segA];
    const int gidB = gid + LIN_THREADS;
    const bool hasB = gidB < ETOT;
    int segB = 0, sB = 0, rkB = 0, offB = 0;
    if (hasB) {
        edge_map(gidB, s0, d0, s1, d1, s2, d2, s3, d3, segB, sB);
        rkB = rank[gidB];
        offB = off[segB];
    }

    // ---- lin staging
    int t, n0; type_of_block64(blockIdx.x, t, n0);
    const int cnt[3] = {NQn, NAn, NKn};
    const long noff[3] = {0, NQn, NQn + NAn};
    const float* X = (t == 0) ? xq : (t == 1) ? xa : xk;
    const int n = cnt[t];

    stage_w<64, 128>(ldsW, wtb + LINT_U + t * 8192, tid);
    stage_f32<128, 64>(ldsX, X, n0, n, tid);
    __syncthreads();

    // ---- fill completion: scattered stores (no atomics), fire-and-forget
    csrc[offA + rkA] = sA;
    if (hasB) csrc[offB + rkB] = sB;

    // ---- lin MFMA
    const int w = tid >> 6, lane = tid & 63;
    f32x4 acc[1][4] = {};
    mfma_coreT<128, 4, 1>(ldsX, ldsW, acc, lane, w);

    const int nodeL = lane & 15, colG = (lane >> 4) * 4;
    int node = n0 + w * 16 + nodeL;
    if (node < n) {
        #pragma unroll
        for (int nf = 0; nf < 4; ++nf) {
            int col0 = nf * 16 + colG;
            float4 bv = *(const float4*)&lin_b[t * 64 + col0];
            ushort4 o;
            o.x = f2bf(fmaxf(acc[0][nf][0] + bv.x, 0.f));
            o.y = f2bf(fmaxf(acc[0][nf][1] + bv.y, 0.f));
            o.z = f2bf(fmaxf(acc[0][nf][2] + bv.z, 0.f));
            o.w = f2bf(fmaxf(acc[0][nf][3] + bv.w, 0.f));
            *(ushort4*)&xsb[(noff[t] + node) * 64 + col0] = o;
        }
    }
}

// ---- qkv split: ONE (product, tile) per block -------------------------------
__global__ void __launch_bounds__(256)
qkv_split(const unsigned short* __restrict__ xsb, const unsigned short* __restrict__ wtb,
          const float* __restrict__ q_b, const float* __restrict__ wfb,
          unsigned short* __restrict__ qbf, unsigned short* __restrict__ kvb)
{
    __shared__ unsigned short ldsX[128 * 64];   // 16 KB
    __shared__ unsigned short ldsW[128 * 64];   // 16 KB
    const int cnt[3] = {NQn, NAn, NKn};
    const long noff[3] = {0, NQn, NQn + NAn};
    const int tid = threadIdx.x;
    const int w = tid >> 6, lane = tid & 63;
    const int nodeL = lane & 15, colG = (lane >> 4) * 4;
    const int b = blockIdx.x;

    if (b < 3908) {
        // ---- q product ----
        int t, n0; type_of_block128(b, t, n0);
        const int n = cnt[t];
        stage_bf16<64>(ldsX, xsb + noff[t] * 64, n0, n, tid);
        stage_w<64, 64>(ldsW, wtb + QT_U + t * 4096, tid);
        __syncthreads();

        f32x4 acc[2][4] = {};
        mfma_coreT<64, 4, 2>(ldsX, ldsW, acc, lane, w);
        #pragma unroll
        for (int mf = 0; mf < 2; ++mf) {
            int node = n0 + w * 32 + mf * 16 + nodeL;
            if (node < n) {
                #pragma unroll
                for (int nf = 0; nf < 4; ++nf) {
                    int col0 = nf * 16 + colG;
                    float4 bv = *(const float4*)&q_b[t * 64 + col0];
                    ushort4 o;
                    o.x = f2bf(acc[mf][nf][0] + bv.x);
                    o.y = f2bf(acc[mf][nf][1] + bv.y);
                    o.z = f2bf(acc[mf][nf][2] + bv.z);
                    o.w = f2bf(acc[mf][nf][3] + bv.w);
                    *(ushort4*)&qbf[(noff[t] + node) * 64 + col0] = o;
                }
            }
        }
    } else {
        // ---- kv product ----
        int kb = b - 3908, r, lb;
        if (kb < 1563)      { r = 0; lb = kb; }
        else if (kb < 2345) { r = 1; lb = kb - 1563; }
        else if (kb < 3127) { r = 2; lb = kb - 2345; }
        else                { r = 3; lb = kb - 3127; }
        const int stt[4] = {2, 0, 0, 1};
        const int st = stt[r];
        const int n0 = lb * 128;
        const int n = cnt[st];
        const long rb = c_rbase[r];

        stage_bf16<64>(ldsX, xsb + noff[st] * 64, n0, n, tid);
        stage_w<128, 64>(ldsW, wtb + WFT_U + r * 8192, tid);
        __syncthreads();

        f32x4 acc[2][8] = {};
        mfma_coreT<64, 8, 2>(ldsX, ldsW, acc, lane, w);
        #pragma unroll
        for (int mf = 0; mf < 2; ++mf) {
            int node = n0 + w * 32 + mf * 16 + nodeL;
            if (node < n) {
                #pragma unroll
                for (int nf = 0; nf < 8; ++nf) {
                    int col0 = nf * 16 + colG;
                    float4 bv = *(const float4*)&wfb[r * 128 + col0];
                    ushort4 o;
                    o.x = f2bf(acc[mf][nf][0] + bv.x);
                    o.y = f2bf(acc[mf][nf][1] + bv.y);
                    o.z = f2bf(acc[mf][nf][2] + bv.z);
                    o.w = f2bf(acc[mf][nf][3] + bv.w);
                    *(ushort4*)&kvb[(rb + node) * 128 + col0] = o;
                }
            }
        }
    }
}

// ---- head: z = beta*(gelu(out) @ a_w + a_b) + (1-beta)*xs; bf16 z copies for pred
__global__ void __launch_bounds__(256)
head_mfma(const unsigned short* __restrict__ outb, const unsigned short* __restrict__ xsb,
          const unsigned short* __restrict__ wtb, const float* __restrict__ a_b,
          const float* __restrict__ skip, float* __restrict__ z,
          unsigned short* __restrict__ zb)
{
    __shared__ unsigned short ldsX[128 * 64];
    __shared__ unsigned short ldsW[64 * 64];
    int t, n0; type_of_block128(blockIdx.x, t, n0);
    const int cnt[3] = {NQn, NAn, NKn};
    const long noff[3] = {0, NQn, NQn + NAn};
    const long zoff[3] = {200000L, 6600000L, 19400000L};
    const int n = cnt[t];
    const int tid = threadIdx.x;

    stage_w<64, 64>(ldsW, wtb + AT_U + t * 4096, tid);
    stage_out_gelu(ldsX, outb + noff[t] * 64, n0, n, tid);
    __syncthreads();

    const int w = tid >> 6, lane = tid & 63;
    f32x4 acc[2][4] = {};
    mfma_coreT<64, 4, 2>(ldsX, ldsW, acc, lane, w);

    const float beta = 1.f / (1.f + expf(-skip[t]));
    const int nodeL = lane & 15, colG = (lane >> 4) * 4;
    #pragma unroll
    for (int mf = 0; mf < 2; ++mf) {
        int node = n0 + w * 32 + mf * 16 + nodeL;
        if (node < n) {
            #pragma unroll
            for (int nf = 0; nf < 4; ++nf) {
                int col0 = nf * 16 + colG;
                float4 bv = *(const float4*)&a_b[t * 64 + col0];
                ushort4 rv = *(const ushort4*)&xsb[(noff[t] + node) * 64 + col0];
                float4 o;
                o.x = beta * (acc[mf][nf][0] + bv.x) + (1.f - beta) * bf2f(rv.x);
                o.y = beta * (acc[mf][nf][1] + bv.y) + (1.f - beta) * bf2f(rv.y);
                o.z = beta * (acc[mf][nf][2] + bv.z) + (1.f - beta) * bf2f(rv.z);
                o.w = beta * (acc[mf][nf][3] + bv.w) + (1.f - beta) * bf2f(rv.w);
                *(float4*)&z[zoff[t] + (long)node * 64 + col0] = o;
                if (t < 2) {
                    ushort4 p;
                    p.x = f2bf(o.x); p.y = f2bf(o.y); p.z = f2bf(o.z); p.w = f2bf(o.w);
                    long zrow = (t == 0) ? (long)node : 100000L + node;
                    *(ushort4*)&zb[zrow * 64 + col0] = p;
                }
            }
        }
    }
}

// ---- scans -------------------------------------------------------------------
__global__ void scan1(const int* __restrict__ in, int* __restrict__ out,
                      int* __restrict__ part, int n)
{
    __shared__ int lds[256];
    const int tid = threadIdx.x;
    const int base = blockIdx.x * 1024 + tid * 4;
    int v[4];
    #pragma unroll
    for (int k = 0; k < 4; ++k) v[k] = (base + k < n) ? in[base + k] : 0;
    int tsum = v[0] + v[1] + v[2] + v[3];
    lds[tid] = tsum;
    __syncthreads();
    for (int off = 1; off < 256; off <<= 1) {
        int t = (tid >= off) ? lds[tid - off] : 0;
        __syncthreads();
        lds[tid] += t;
        __syncthreads();
    }
    int excl = lds[tid] - tsum;
    #pragma unroll
    for (int k = 0; k < 4; ++k) {
        if (base + k < n) out[base + k] = excl;
        excl += v[k];
    }
    if (tid == 255) part[blockIdx.x] = lds[255];
}

__global__ void scan2(int* __restrict__ part, int nb)   // nb <= 1024
{
    __shared__ int lds[256];
    const int tid = threadIdx.x;
    const int base = tid * 4;
    int v[4];
    #pragma unroll
    for (int k = 0; k < 4; ++k) v[k] = (base + k < nb) ? part[base + k] : 0;
    int tsum = v[0] + v[1] + v[2] + v[3];
    lds[tid] = tsum;
    __syncthreads();
    for (int off = 1; off < 256; off <<= 1) {
        int t = (tid >= off) ? lds[tid - off] : 0;
        __syncthreads();
        lds[tid] += t;
        __syncthreads();
    }
    int excl = lds[tid] - tsum;
    #pragma unroll
    for (int k = 0; k < 4; ++k) {
        if (base + k < nb) part[base + k] = excl;
        excl += v[k];
    }
}

__global__ void scan3(int* __restrict__ off, const int* __restrict__ part, int n, int E)
{
    int i = blockIdx.x * 256 + threadIdx.x;
    if (i < n) off[i] += part[i >> 10];
    if (i == 0) off[n] = E;
}

// ---- fused attention: one 16-lane group per destination node ----------------
// No max-tracking (shift-invariant softmax; alphas O(1), clamped at 115 in exp2
// domain). p_rel*scale*log2e folded into q. 4-edge ILP per iteration.
__device__ inline void attn_node(const int* __restrict__ csrc, int begin, int end,
                                 const unsigned short* __restrict__ kvt,
                                 const float qv[4], int j, float res[4])
{
    float ss = 0.f, a0 = 0.f, a1 = 0.f, a2 = 0.f, a3 = 0.f;

    for (int t = begin; t < end; t += 4) {
        bool v1 = (t + 1 < end), v2 = (t + 2 < end), v3 = (t + 3 < end);
        int s0 = csrc[t];
        int s1 = csrc[v1 ? t + 1 : t];
        int s2 = csrc[v2 ? t + 2 : t];
        int s3 = csrc[v3 ? t + 3 : t];
        uint4 k0 = *(const uint4*)(kvt + (long)s0 * 128 + j * 8);
        uint4 k1 = *(const uint4*)(kvt + (long)s1 * 128 + j * 8);
        uint4 k2 = *(const uint4*)(kvt + (long)s2 * 128 + j * 8);
        uint4 k3 = *(const uint4*)(kvt + (long)s3 * 128 + j * 8);

        float p0 = __uint_as_float(k0.x << 16) * qv[0] + __uint_as_float(k0.y << 16) * qv[1]
                 + __uint_as_float(k0.z << 16) * qv[2] + __uint_as_float(k0.w << 16) * qv[3];
        float p1 = __uint_as_float(k1.x << 16) * qv[0] + __uint_as_float(k1.y << 16) * qv[1]
                 + __uint_as_float(k1.z << 16) * qv[2] + __uint_as_float(k1.w << 16) * qv[3];
        float p2 = __uint_as_float(k2.x << 16) * qv[0] + __uint_as_float(k2.y << 16) * qv[1]
                 + __uint_as_float(k2.z << 16) * qv[2] + __uint_as_float(k2.w << 16) * qv[3];
        float p3 = __uint_as_float(k3.x << 16) * qv[0] + __uint_as_float(k3.y << 16) * qv[1]
                 + __uint_as_float(k3.z << 16) * qv[2] + __uint_as_float(k3.w << 16) * qv[3];

        p0 += __shfl_xor(p0, 1);  p1 += __shfl_xor(p1, 1);
        p2 += __shfl_xor(p2, 1);  p3 += __shfl_xor(p3, 1);
        p0 += __shfl_xor(p0, 2);  p1 += __shfl_xor(p1, 2);
        p2 += __shfl_xor(p2, 2);  p3 += __shfl_xor(p3, 2);
        p0 += __shfl_xor(p0, 4);  p1 += __shfl_xor(p1, 4);
        p2 += __shfl_xor(p2, 4);  p3 += __shfl_xor(p3, 4);

        float w0 = exp2f(fminf(p0, 115.f));
        float w1 = v1 ? exp2f(fminf(p1, 115.f)) : 0.f;
        float w2 = v2 ? exp2f(fminf(p2, 115.f)) : 0.f;
        float w3 = v3 ? exp2f(fminf(p3, 115.f)) : 0.f;

        ss += (w0 + w1) + (w2 + w3);
        a0 += w0 * __uint_as_float(k0.x & 0xffff0000u) + w1 * __uint_as_float(k1.x & 0xffff0000u)
            + w2 * __uint_as_float(k2.x & 0xffff0000u) + w3 * __uint_as_float(k3.x & 0xffff0000u);
        a1 += w0 * __uint_as_float(k0.y & 0xffff0000u) + w1 * __uint_as_float(k1.y & 0xffff0000u)
            + w2 * __uint_as_float(k2.y & 0xffff0000u) + w3 * __uint_as_float(k3.y & 0xffff0000u);
        a2 += w0 * __uint_as_float(k0.z & 0xffff0000u) + w1 * __uint_as_float(k1.z & 0xffff0000u)
            + w2 * __uint_as_float(k2.z & 0xffff0000u) + w3 * __uint_as_float(k3.z & 0xffff0000u);
        a3 += w0 * __uint_as_float(k0.w & 0xffff0000u) + w1 * __uint_as_float(k1.w & 0xffff0000u)
            + w2 * __uint_as_float(k2.w & 0xffff0000u) + w3 * __uint_as_float(k3.w & 0xffff0000u);
    }

    float inv = 1.f / (ss + 1e-16f);
    res[0] = a0 * inv; res[1] = a1 * inv; res[2] = a2 * inv; res[3] = a3 * inv;
}

__global__ void __launch_bounds__(256)
attn_all(const int* __restrict__ off, const int* __restrict__ csrc,
         const unsigned short* __restrict__ qbf, const unsigned short* __restrict__ kv,
         const float* __restrict__ prel, float scale, unsigned short* __restrict__ outb)
{
    const int tid = threadIdx.x;
    const int nid = blockIdx.x * 16 + (tid >> 4);   // 16 nodes per block
    const int j = tid & 15;
    const int h = j >> 3;
    const float l2e = 1.4426950408889634f;

    long row; int segA, segB = -1; long kbA, kbB = 0; float psA, psB = 0.f;
    if (nid < 100000) {
        row = nid;
        segA = nid;            kbA = c_rbase[0]; psA = prel[0 + h] * scale * l2e;
        segB = 500000 + nid;   kbB = c_rbase[3]; psB = prel[6 + h] * scale * l2e;
    } else if (nid < 300000) {
        int kk = nid - 100000;
        row = 300000 + kk;
        segA = 100000 + kk;    kbA = c_rbase[1]; psA = prel[2 + h] * scale * l2e;
    } else {
        int aa = nid - 300000;
        row = 100000 + aa;
        segA = 300000 + aa;    kbA = c_rbase[2]; psA = prel[4 + h] * scale * l2e;
    }

    ushort4 q4 = *(const ushort4*)&qbf[row * 64 + 4 * j];
    float qraw[4] = {bf2f(q4.x), bf2f(q4.y), bf2f(q4.z), bf2f(q4.w)};

    float res[4];
    {
        float qv[4] = {qraw[0] * psA, qraw[1] * psA, qraw[2] * psA, qraw[3] * psA};
        attn_node(csrc, off[segA], off[segA + 1], kv + kbA * 128, qv, j, res);
    }
    if (segB >= 0) {
        float qv[4] = {qraw[0] * psB, qraw[1] * psB, qraw[2] * psB, qraw[3] * psB};
        float r2[4];
        attn_node(csrc, off[segB], off[segB + 1], kv + kbB * 128, qv, j, r2);
        res[0] += r2[0]; res[1] += r2[1]; res[2] += r2[2]; res[3] += r2[3];
    }

    ushort4 o;
    o.x = f2bf(res[0]); o.y = f2bf(res[1]); o.z = f2bf(res[2]); o.w = f2bf(res[3]);
    *(ushort4*)&outb[row * 64 + 4 * j] = o;
}

// ---- link prediction (bf16 z gathers) ---------------------------------------
__global__ void pred_all(const int* __restrict__ psrc, const int* __restrict__ pdst,
                         const int* __restrict__ nsrc, const int* __restrict__ ndst,
                         const unsigned short* __restrict__ zb, float* __restrict__ out)
{
    int t = blockIdx.x * 256 + threadIdx.x;
    int g = t >> 3, lane = t & 7;
    if (g >= EPc + ENc) return;
    int s, d;
    if (g < EPc) { s = psrc[g]; d = pdst[g]; }
    else         { int gg = g - EPc; s = nsrc[gg]; d = ndst[gg]; }
    uint4 zs = *(const uint4*)&zb[(long)s * 64 + lane * 8];
    uint4 zd = *(const uint4*)&zb[(100000L + d) * 64 + lane * 8];
    float p = 0.f;
    p += bf2f((unsigned short)(zs.x & 0xffffu)) * bf2f((unsigned short)(zd.x & 0xffffu));
    p += bf2f((unsigned short)(zs.x >> 16))     * bf2f((unsigned short)(zd.x >> 16));
    p += bf2f((unsigned short)(zs.y & 0xffffu)) * bf2f((unsigned short)(zd.y & 0xffffu));
    p += bf2f((unsigned short)(zs.y >> 16))     * bf2f((unsigned short)(zd.y >> 16));
    p += bf2f((unsigned short)(zs.z & 0xffffu)) * bf2f((unsigned short)(zd.z & 0xffffu));
    p += bf2f((unsigned short)(zs.z >> 16))     * bf2f((unsigned short)(zd.z >> 16));
    p += bf2f((unsigned short)(zs.w & 0xffffu)) * bf2f((unsigned short)(zd.w & 0xffffu));
    p += bf2f((unsigned short)(zs.w >> 16))     * bf2f((unsigned short)(zd.w >> 16));
    p += __shfl_xor(p, 1);
    p += __shfl_xor(p, 2);
    p += __shfl_xor(p, 4);
    if (lane == 0) out[g] = 1.f / (1.f + expf(-p));
}

} // namespace

extern "C" void kernel_launch(void* const* d_in, const int* in_sizes, int n_in,
                              void* d_out, int out_size, void* d_ws, size_t ws_size,
                              hipStream_t stream)
{
    const float* xq    = (const float*)d_in[0];
    const float* xa    = (const float*)d_in[1];
    const float* xk    = (const float*)d_in[2];
    const float* lin_w = (const float*)d_in[3];
    const float* lin_b = (const float*)d_in[4];
    const float* k_w   = (const float*)d_in[5];
    const float* k_b   = (const float*)d_in[6];
    const float* q_w   = (const float*)d_in[7];
    const float* q_b   = (const float*)d_in[8];
    const float* v_w   = (const float*)d_in[9];
    const float* v_b   = (const float*)d_in[10];
    const float* a_w   = (const float*)d_in[11];
    const float* a_b   = (const float*)d_in[12];
    const float* a_rel = (const float*)d_in[13];
    const float* m_rel = (const float*)d_in[14];
    const float* p_rel = (const float*)d_in[15];
    const float* skip  = (const float*)d_in[16];
    const int* esrc[4] = {(const int*)d_in[17], (const int*)d_in[19], (const int*)d_in[21], (const int*)d_in[23]};
    const int* edst[4] = {(const int*)d_in[18], (const int*)d_in[20], (const int*)d_in[22], (const int*)d_in[24]};
    const int* pos_src = (const int*)d_in[25];
    const int* pos_dst = (const int*)d_in[26];
    const int* neg_src = (const int*)d_in[27];
    const int* neg_dst = (const int*)d_in[28];

    float* ws   = (float*)d_ws;
    float* outp = (float*)d_out;
    int*   wi   = (int*)(ws + INT_OFF);
    unsigned short* xsb  = (unsigned short*)(ws + XSB_OFF);
    unsigned short* outb = (unsigned short*)(ws + OUTB_OFF);
    unsigned short* qbf  = (unsigned short*)(ws + QBF_OFF);
    unsigned short* kvb  = (unsigned short*)(ws + KV_OFF);
    unsigned short* zbb  = (unsigned short*)(ws + ZB_OFF);
    unsigned short* wtb  = (unsigned short*)(ws + WTB_OFF);
    float*          wfb  = ws + WFB_OFF;

    // zero degree counters (memset-clean lines keep atomics fast)
    hipMemsetAsync(wi + DEG_I, 0, 600000L * sizeof(int), stream);

    // stage 1: fused rel weights + transposes + CSR count (stores per-edge rank)
    prep_count<<<196 + 9375, 256, 0, stream>>>(
        lin_w, q_w, a_w, k_w, k_b, v_w, v_b, a_rel, m_rel, wtb, wfb,
        edst[0], edst[1], edst[2], edst[3], wi + DEG_I, wi + RANK_I);

    // CSR offsets
    const int nb = (NSEG + 1023) / 1024;   // 586
    scan1<<<nb, 256, 0, stream>>>(wi + DEG_I, wi + OFFS_I, wi + PART_I, NSEG);
    scan2<<<1, 256, 0, stream>>>(wi + PART_I, nb);
    scan3<<<(NSEG + 255) / 256, 256, 0, stream>>>(wi + OFFS_I, wi + PART_I, NSEG, ETOT);

    // stage 2: lin GEMM + atomic-free CSR fill carried by every thread
    lin_fill<<<7813, 256, 0, stream>>>(
        esrc[0], edst[0], esrc[1], edst[1], esrc[2], edst[2], esrc[3], edst[3],
        wi + OFFS_I, wi + RANK_I, wi + CSRC_I,
        xq, xa, xk, wtb, lin_b, xsb);

    // q + kv as one-block-per-product
    qkv_split<<<8598, 256, 0, stream>>>(xsb, wtb, q_b, wfb, qbf, kvb);

    // merged attention: one 16-lane group per destination node
    const float scale = 0.17677669529663687f;   // 1/sqrt(32)
    attn_all<<<31250, 256, 0, stream>>>(wi + OFFS_I, wi + CSRC_I, qbf, kvb,
                                        p_rel, scale, outb);

    // output head (+ bf16 z copies for pred)
    head_mfma<<<3908, 256, 0, stream>>>(outb, xsb, wtb, a_b, skip, outp, zbb);

    // link predictions
    pred_all<<<(200000 * 8 + 255) / 256, 256, 0, stream>>>(
        pos_src, pos_dst, neg_src, neg_dst, zbb, outp);
}

// Round 17
// 531.903 us; speedup vs baseline: 1.1942x; 1.0322x over previous
//
#include <hip/hip_runtime.h>
#include <math.h>

namespace {

constexpr int NQn = 100000, NAn = 200000, NKn = 200000;
constexpr int EPc = 100000, ENc = 100000;
constexpr int ETOT = 2400000, NSEG = 600000;
constexpr int LIN_THREADS = 7813 * 256;   // 2,000,128

// ---- workspace layout (float element offsets) ----
constexpr long XSB_OFF  = 0;            // 16M floats = 32M bf16 xs
constexpr long OUTB_OFF = 16000000;     // 16M floats = 32M bf16 attn out
constexpr long QBF_OFF  = 32000000;     // 16M floats = 32M bf16 q
constexpr long KV_OFF   = 48000000;     // 38.4M floats = 600064 x 128 bf16
constexpr long ZB_OFF   = 86500000;     // 9.6M floats = 300000 x 64 bf16 (zq|za)
constexpr long WTB_OFF  = 96200000;     // bf16 transposed weights
constexpr long WFB_OFF  = 96250000;     // fp32 fused kv bias (512)
constexpr long INT_OFF  = 96300000;     // int region
// int offsets within (int*)(ws + INT_OFF):
constexpr long DEG_I  = 0;          //   600,000
constexpr long OFFS_I = 600064;     //   600,064
constexpr long PART_I = 1200128;    //     1,024
constexpr long RANK_I = 1201152;    // 2,400,000
constexpr long CSRC_I = 3601152;    // 2,400,000

// wtb ushort offsets
constexpr int LINT_U = 0;        // 3 x 64 x 128
constexpr int QT_U   = 24576;    // 3 x 64 x 64
constexpr int AT_U   = 36864;    // 3 x 64 x 64
constexpr int WFT_U  = 49152;    // 4 x 128 x 64

__constant__ long c_rbase[4] = {0, 200000, 300032, 400064};

typedef __attribute__((ext_vector_type(8))) short bf16x8;
typedef __attribute__((ext_vector_type(4))) float f32x4;
typedef __attribute__((ext_vector_type(4))) unsigned int u32x4;
typedef __attribute__((ext_vector_type(2))) unsigned int u32x2;

__device__ inline f32x4 mfma16(bf16x8 a, bf16x8 b, f32x4 c) {
    return __builtin_amdgcn_mfma_f32_16x16x32_bf16(a, b, c, 0, 0, 0);
}

__device__ inline float gelu_f(float x) {
    return 0.5f * x * (1.0f + erff(x * 0.7071067811865475f));
}
__device__ inline float bf2f(unsigned short u) {
    return __uint_as_float(((unsigned)u) << 16);
}
__device__ inline unsigned short f2bf(float f) {
    unsigned u = __float_as_uint(f);
    return (unsigned short)((u + 0x7fffu + ((u >> 16) & 1u)) >> 16);
}

// block -> node-type mapping, 128-row tiles: counts {782, 1563, 1563}
__device__ inline void type_of_block128(int b, int& t, int& n0) {
    if (b < 782)       { t = 0; n0 = b * 128; }
    else if (b < 2345) { t = 1; n0 = (b - 782) * 128; }
    else               { t = 2; n0 = (b - 2345) * 128; }
}
// block -> node-type mapping, 64-row tiles: counts {1563, 3125, 3125}
__device__ inline void type_of_block64(int b, int& t, int& n0) {
    if (b < 1563)      { t = 0; n0 = b * 64; }
    else if (b < 4688) { t = 1; n0 = (b - 1563) * 64; }
    else               { t = 2; n0 = (b - 4688) * 64; }
}

// ---- staging helpers (XOR-swizzled LDS, 16B chunks) ----
template<int K>
__device__ inline void stage_bf16(unsigned short* lds, const unsigned short* src,
                                  int n0, int n, int tid)
{
    constexpr int CPR = K / 8;
    for (int c = tid; c < 128 * CPR; c += 256) {
        int row = c / CPR, kc = c % CPR;
        int node = n0 + row; if (node > n - 1) node = n - 1;
        uint4 v = *(const uint4*)&src[(long)node * K + kc * 8];
        int byte = (row * K + kc * 8) * 2;
        *(uint4*)((char*)lds + (byte ^ ((row & 7) << 4))) = v;
    }
}

// bf16 input + gelu applied during staging (K=64)
__device__ inline void stage_out_gelu(unsigned short* lds, const unsigned short* src,
                                      int n0, int n, int tid)
{
    for (int c = tid; c < 128 * 8; c += 256) {
        int row = c >> 3, kc = c & 7;
        int node = n0 + row; if (node > n - 1) node = n - 1;
        uint4 v = *(const uint4*)&src[(long)node * 64 + kc * 8];
        float f0 = gelu_f(bf2f((unsigned short)(v.x & 0xffffu)));
        float f1 = gelu_f(bf2f((unsigned short)(v.x >> 16)));
        float f2 = gelu_f(bf2f((unsigned short)(v.y & 0xffffu)));
        float f3 = gelu_f(bf2f((unsigned short)(v.y >> 16)));
        float f4 = gelu_f(bf2f((unsigned short)(v.z & 0xffffu)));
        float f5 = gelu_f(bf2f((unsigned short)(v.z >> 16)));
        float f6 = gelu_f(bf2f((unsigned short)(v.w & 0xffffu)));
        float f7 = gelu_f(bf2f((unsigned short)(v.w >> 16)));
        uint4 o;
        o.x = (unsigned)f2bf(f0) | ((unsigned)f2bf(f1) << 16);
        o.y = (unsigned)f2bf(f2) | ((unsigned)f2bf(f3) << 16);
        o.z = (unsigned)f2bf(f4) | ((unsigned)f2bf(f5) << 16);
        o.w = (unsigned)f2bf(f6) | ((unsigned)f2bf(f7) << 16);
        int byte = (row * 64 + kc * 8) * 2;
        *(uint4*)((char*)lds + (byte ^ ((row & 7) << 4))) = o;
    }
}

// fp32 input staged as bf16, NON-TEMPORAL reads (x is read exactly once)
template<int K, int ROWS>
__device__ inline void stage_f32_nt(unsigned short* lds, const float* src,
                                    int n0, int n, int tid)
{
    constexpr int CPR = K / 8;
    for (int c = tid; c < ROWS * CPR; c += 256) {
        int row = c / CPR, kc = c % CPR;
        int node = n0 + row; if (node > n - 1) node = n - 1;
        const f32x4* sp = (const f32x4*)&src[(long)node * K + kc * 8];
        f32x4 f0 = __builtin_nontemporal_load(sp);
        f32x4 f1 = __builtin_nontemporal_load(sp + 1);
        uint4 v;
        v.x = (unsigned)f2bf(f0.x) | ((unsigned)f2bf(f0.y) << 16);
        v.y = (unsigned)f2bf(f0.z) | ((unsigned)f2bf(f0.w) << 16);
        v.z = (unsigned)f2bf(f1.x) | ((unsigned)f2bf(f1.y) << 16);
        v.w = (unsigned)f2bf(f1.z) | ((unsigned)f2bf(f1.w) << 16);
        int byte = (row * K + kc * 8) * 2;
        *(uint4*)((char*)lds + (byte ^ ((row & 7) << 4))) = v;
    }
}

template<int N, int K>
__device__ inline void stage_w(unsigned short* lds, const unsigned short* wt, int tid)
{
    constexpr int CPR = K / 8;
    for (int c = tid; c < N * CPR; c += 256) {
        int nr = c / CPR, kc = c % CPR;
        uint4 v = *(const uint4*)&wt[nr * K + kc * 8];
        int byte = (nr * K + kc * 8) * 2;
        *(uint4*)((char*)lds + (byte ^ ((nr & 7) << 4))) = v;
    }
}

// ---- MFMA core (TRANSPOSED operand order): wave w covers rows
// [w*16*MF, w*16*MF + 16*MF). acc[mf][nf]: col(lane&15)=node,
// rows=(lane>>4)*4+i = 4 consecutive out cols.
template<int K, int NF, int MF>
__device__ inline void mfma_coreT(const unsigned short* ldsX, const unsigned short* ldsW,
                                  f32x4 (&acc)[MF][NF], int lane, int w)
{
    const int lrow = lane & 15, lk = (lane >> 4) * 8;
    #pragma unroll
    for (int ks = 0; ks < K / 32; ++ks) {
        bf16x8 a[MF], b[NF];
        #pragma unroll
        for (int mf = 0; mf < MF; ++mf) {
            int row = w * (16 * MF) + mf * 16 + lrow;
            int byte = (row * K + ks * 32 + lk) * 2;
            a[mf] = *(const bf16x8*)((const char*)ldsX + (byte ^ ((row & 7) << 4)));
        }
        #pragma unroll
        for (int nf = 0; nf < NF; ++nf) {
            int nr = nf * 16 + lrow;
            int byte = (nr * K + ks * 32 + lk) * 2;
            b[nf] = *(const bf16x8*)((const char*)ldsW + (byte ^ ((nr & 7) << 4)));
        }
        #pragma unroll
        for (int mf = 0; mf < MF; ++mf)
            #pragma unroll
            for (int nf = 0; nf < NF; ++nf)
                acc[mf][nf] = mfma16(b[nf], a[mf], acc[mf][nf]);   // swapped!
    }
}

// ---- edge id -> segment (+source) mapping ------------------------------------
__device__ inline void edge_map(int gid,
                                const int* __restrict__ s0, const int* __restrict__ d0,
                                const int* __restrict__ s1, const int* __restrict__ d1,
                                const int* __restrict__ s2, const int* __restrict__ d2,
                                const int* __restrict__ s3, const int* __restrict__ d3,
                                int& seg, int& s)
{
    if (gid < 800000)       { seg = d0[gid];                    s = s0[gid]; }
    else if (gid < 1600000) { seg = 100000 + d1[gid - 800000];  s = s1[gid - 800000]; }
    else if (gid < 2000000) { seg = 300000 + d2[gid - 1600000]; s = s2[gid - 1600000]; }
    else                    { seg = 500000 + d3[gid - 2000000]; s = s3[gid - 2000000]; }
}
__device__ inline int edge_seg(int gid,
                               const int* __restrict__ d0, const int* __restrict__ d1,
                               const int* __restrict__ d2, const int* __restrict__ d3)
{
    if (gid < 800000)       return d0[gid];
    else if (gid < 1600000) return 100000 + d1[gid - 800000];
    else if (gid < 2000000) return 300000 + d2[gid - 1600000];
    else                    return 500000 + d3[gid - 2000000];
}

// ---- merged: fused relation weights + transposes + CSR count (stores rank) ---
// blocks [0,4): fused rel W; [4,196): transposes; [196, 196+9375): csr count
__global__ void prep_count(const float* __restrict__ lin_w, const float* __restrict__ q_w,
                           const float* __restrict__ a_w,
                           const float* __restrict__ kw, const float* __restrict__ kb,
                           const float* __restrict__ vw, const float* __restrict__ vb,
                           const float* __restrict__ a_rel, const float* __restrict__ m_rel,
                           unsigned short* __restrict__ wtb, float* __restrict__ wfb,
                           const int* __restrict__ d0, const int* __restrict__ d1,
                           const int* __restrict__ d2, const int* __restrict__ d3,
                           int* __restrict__ deg, int* __restrict__ rank)
{
    const int tid = threadIdx.x;
    if (blockIdx.x < 4) {
        const int r = blockIdx.x;
        const int st_tab[4] = {2, 0, 0, 1};
        const int st = st_tab[r];
        for (int idx = tid; idx < 8192; idx += 256) {
            int d = idx >> 7, c = idx & 127;
            int i = c >> 1, which = c & 1;
            int h = i >> 5, e = i & 31;
            const float* w   = (which ? vw : kw) + st * 4096;
            const float* rel = (which ? m_rel : a_rel) + r * 2048;
            float s = 0.f;
            #pragma unroll
            for (int c32 = 0; c32 < 32; ++c32)
                s += w[d * 64 + h * 32 + c32] * rel[h * 1024 + c32 * 32 + e];
            wtb[WFT_U + r * 8192 + c * 64 + d] = f2bf(s);
        }
        for (int idx = tid; idx < 128; idx += 256) {
            int i = idx >> 1, which = idx & 1;
            int h = i >> 5, e = i & 31;
            const float* b   = (which ? vb : kb) + st * 64;
            const float* rel = (which ? m_rel : a_rel) + r * 2048;
            float s = 0.f;
            #pragma unroll
            for (int c32 = 0; c32 < 32; ++c32)
                s += b[h * 32 + c32] * rel[h * 1024 + c32 * 32 + e];
            wfb[r * 128 + idx] = s;
        }
    } else if (blockIdx.x < 196) {
        int i = (blockIdx.x - 4) * 256 + tid;
        if (i < 24576) {
            int t = i / 8192, rem = i % 8192, nn = rem >> 7, kk = rem & 127;
            wtb[LINT_U + i] = f2bf(lin_w[t * 8192 + kk * 64 + nn]);
        } else if (i < 36864) {
            int j = i - 24576;
            int t = j / 4096, rem = j % 4096, nn = rem >> 6, kk = rem & 63;
            wtb[QT_U + j] = f2bf(q_w[t * 4096 + kk * 64 + nn]);
        } else if (i < 49152) {
            int j = i - 36864;
            int t = j / 4096, rem = j % 4096, nn = rem >> 6, kk = rem & 63;
            wtb[AT_U + j] = f2bf(a_w[t * 4096 + kk * 64 + nn]);
        }
    } else {
        int gid = (blockIdx.x - 196) * 256 + tid;
        if (gid < ETOT) {
            int seg = edge_seg(gid, d0, d1, d2, d3);
            rank[gid] = atomicAdd(&deg[seg], 1);
        }
    }
}

// ---- fused: lin GEMM + atomic-free CSR fill carried by every thread ----------
__global__ void __launch_bounds__(256)
lin_fill(const int* __restrict__ s0, const int* __restrict__ d0,
         const int* __restrict__ s1, const int* __restrict__ d1,
         const int* __restrict__ s2, const int* __restrict__ d2,
         const int* __restrict__ s3, const int* __restrict__ d3,
         const int* __restrict__ off, const int* __restrict__ rank,
         int* __restrict__ csrc,
         const float* __restrict__ xq, const float* __restrict__ xa,
         const float* __restrict__ xk, const unsigned short* __restrict__ wtb,
         const float* __restrict__ lin_b, unsigned short* __restrict__ xsb)
{
    __shared__ unsigned short ldsX[64 * 128];   // 16 KB
    __shared__ unsigned short ldsW[64 * 128];   // 16 KB
    const int tid = threadIdx.x;
    const int gid = blockIdx.x * 256 + tid;

    // ---- fill: issue edge loads + scattered off gathers early
    int segA, sA;
    edge_map(gid, s0, d0, s1, d1, s2, d2, s3, d3, segA, sA);
    int rkA = rank[gid];
    int offA = off[segA];
    const int gidB = gid + LIN_THREADS;
    const bool hasB = gidB < ETOT;
    int segB = 0, sB = 0, rkB = 0, offB = 0;
    if (hasB) {
        edge_map(gidB, s0, d0, s1, d1, s2, d2, s3, d3, segB, sB);
        rkB = rank[gidB];
        offB = off[segB];
    }

    // ---- lin staging (x reads non-temporal: read-once stream)
    int t, n0; type_of_block64(blockIdx.x, t, n0);
    const int cnt[3] = {NQn, NAn, NKn};
    const long noff[3] = {0, NQn, NQn + NAn};
    const float* X = (t == 0) ? xq : (t == 1) ? xa : xk;
    const int n = cnt[t];

    stage_w<64, 128>(ldsW, wtb + LINT_U + t * 8192, tid);
    stage_f32_nt<128, 64>(ldsX, X, n0, n, tid);
    __syncthreads();

    // ---- fill completion: scattered stores (no atomics), fire-and-forget
    csrc[offA + rkA] = sA;
    if (hasB) csrc[offB + rkB] = sB;

    // ---- lin MFMA
    const int w = tid >> 6, lane = tid & 63;
    f32x4 acc[1][4] = {};
    mfma_coreT<128, 4, 1>(ldsX, ldsW, acc, lane, w);

    const int nodeL = lane & 15, colG = (lane >> 4) * 4;
    int node = n0 + w * 16 + nodeL;
    if (node < n) {
        #pragma unroll
        for (int nf = 0; nf < 4; ++nf) {
            int col0 = nf * 16 + colG;
            float4 bv = *(const float4*)&lin_b[t * 64 + col0];
            ushort4 o;
            o.x = f2bf(fmaxf(acc[0][nf][0] + bv.x, 0.f));
            o.y = f2bf(fmaxf(acc[0][nf][1] + bv.y, 0.f));
            o.z = f2bf(fmaxf(acc[0][nf][2] + bv.z, 0.f));
            o.w = f2bf(fmaxf(acc[0][nf][3] + bv.w, 0.f));
            *(ushort4*)&xsb[(noff[t] + node) * 64 + col0] = o;
        }
    }
}

// ---- qkv split: ONE (product, tile) per block -------------------------------
__global__ void __launch_bounds__(256)
qkv_split(const unsigned short* __restrict__ xsb, const unsigned short* __restrict__ wtb,
          const float* __restrict__ q_b, const float* __restrict__ wfb,
          unsigned short* __restrict__ qbf, unsigned short* __restrict__ kvb)
{
    __shared__ unsigned short ldsX[128 * 64];   // 16 KB
    __shared__ unsigned short ldsW[128 * 64];   // 16 KB
    const int cnt[3] = {NQn, NAn, NKn};
    const long noff[3] = {0, NQn, NQn + NAn};
    const int tid = threadIdx.x;
    const int w = tid >> 6, lane = tid & 63;
    const int nodeL = lane & 15, colG = (lane >> 4) * 4;
    const int b = blockIdx.x;

    if (b < 3908) {
        // ---- q product ----
        int t, n0; type_of_block128(b, t, n0);
        const int n = cnt[t];
        stage_bf16<64>(ldsX, xsb + noff[t] * 64, n0, n, tid);
        stage_w<64, 64>(ldsW, wtb + QT_U + t * 4096, tid);
        __syncthreads();

        f32x4 acc[2][4] = {};
        mfma_coreT<64, 4, 2>(ldsX, ldsW, acc, lane, w);
        #pragma unroll
        for (int mf = 0; mf < 2; ++mf) {
            int node = n0 + w * 32 + mf * 16 + nodeL;
            if (node < n) {
                #pragma unroll
                for (int nf = 0; nf < 4; ++nf) {
                    int col0 = nf * 16 + colG;
                    float4 bv = *(const float4*)&q_b[t * 64 + col0];
                    ushort4 o;
                    o.x = f2bf(acc[mf][nf][0] + bv.x);
                    o.y = f2bf(acc[mf][nf][1] + bv.y);
                    o.z = f2bf(acc[mf][nf][2] + bv.z);
                    o.w = f2bf(acc[mf][nf][3] + bv.w);
                    *(ushort4*)&qbf[(noff[t] + node) * 64 + col0] = o;
                }
            }
        }
    } else {
        // ---- kv product ----
        int kb = b - 3908, r, lb;
        if (kb < 1563)      { r = 0; lb = kb; }
        else if (kb < 2345) { r = 1; lb = kb - 1563; }
        else if (kb < 3127) { r = 2; lb = kb - 2345; }
        else                { r = 3; lb = kb - 3127; }
        const int stt[4] = {2, 0, 0, 1};
        const int st = stt[r];
        const int n0 = lb * 128;
        const int n = cnt[st];
        const long rb = c_rbase[r];

        stage_bf16<64>(ldsX, xsb + noff[st] * 64, n0, n, tid);
        stage_w<128, 64>(ldsW, wtb + WFT_U + r * 8192, tid);
        __syncthreads();

        f32x4 acc[2][8] = {};
        mfma_coreT<64, 8, 2>(ldsX, ldsW, acc, lane, w);
        #pragma unroll
        for (int mf = 0; mf < 2; ++mf) {
            int node = n0 + w * 32 + mf * 16 + nodeL;
            if (node < n) {
                #pragma unroll
                for (int nf = 0; nf < 8; ++nf) {
                    int col0 = nf * 16 + colG;
                    float4 bv = *(const float4*)&wfb[r * 128 + col0];
                    ushort4 o;
                    o.x = f2bf(acc[mf][nf][0] + bv.x);
                    o.y = f2bf(acc[mf][nf][1] + bv.y);
                    o.z = f2bf(acc[mf][nf][2] + bv.z);
                    o.w = f2bf(acc[mf][nf][3] + bv.w);
                    *(ushort4*)&kvb[(rb + node) * 128 + col0] = o;
                }
            }
        }
    }
}

// ---- head: z = beta*(gelu(out) @ a_w + a_b) + (1-beta)*xs; bf16 z copies for pred
__global__ void __launch_bounds__(256)
head_mfma(const unsigned short* __restrict__ outb, const unsigned short* __restrict__ xsb,
          const unsigned short* __restrict__ wtb, const float* __restrict__ a_b,
          const float* __restrict__ skip, float* __restrict__ z,
          unsigned short* __restrict__ zb)
{
    __shared__ unsigned short ldsX[128 * 64];
    __shared__ unsigned short ldsW[64 * 64];
    int t, n0; type_of_block128(blockIdx.x, t, n0);
    const int cnt[3] = {NQn, NAn, NKn};
    const long noff[3] = {0, NQn, NQn + NAn};
    const long zoff[3] = {200000L, 6600000L, 19400000L};
    const int n = cnt[t];
    const int tid = threadIdx.x;

    stage_w<64, 64>(ldsW, wtb + AT_U + t * 4096, tid);
    stage_out_gelu(ldsX, outb + noff[t] * 64, n0, n, tid);
    __syncthreads();

    const int w = tid >> 6, lane = tid & 63;
    f32x4 acc[2][4] = {};
    mfma_coreT<64, 4, 2>(ldsX, ldsW, acc, lane, w);

    const float beta = 1.f / (1.f + expf(-skip[t]));
    const int nodeL = lane & 15, colG = (lane >> 4) * 4;
    #pragma unroll
    for (int mf = 0; mf < 2; ++mf) {
        int node = n0 + w * 32 + mf * 16 + nodeL;
        if (node < n) {
            #pragma unroll
            for (int nf = 0; nf < 4; ++nf) {
                int col0 = nf * 16 + colG;
                float4 bv = *(const float4*)&a_b[t * 64 + col0];
                ushort4 rv = *(const ushort4*)&xsb[(noff[t] + node) * 64 + col0];
                f32x4 o;
                o.x = beta * (acc[mf][nf][0] + bv.x) + (1.f - beta) * bf2f(rv.x);
                o.y = beta * (acc[mf][nf][1] + bv.y) + (1.f - beta) * bf2f(rv.y);
                o.z = beta * (acc[mf][nf][2] + bv.z) + (1.f - beta) * bf2f(rv.z);
                o.w = beta * (acc[mf][nf][3] + bv.w) + (1.f - beta) * bf2f(rv.w);
                // z is never re-read on device: non-temporal store
                __builtin_nontemporal_store(o, (f32x4*)&z[zoff[t] + (long)node * 64 + col0]);
                if (t < 2) {
                    ushort4 p;
                    p.x = f2bf(o.x); p.y = f2bf(o.y); p.z = f2bf(o.z); p.w = f2bf(o.w);
                    long zrow = (t == 0) ? (long)node : 100000L + node;
                    *(ushort4*)&zb[zrow * 64 + col0] = p;
                }
            }
        }
    }
}

// ---- scans -------------------------------------------------------------------
__global__ void scan1(const int* __restrict__ in, int* __restrict__ out,
                      int* __restrict__ part, int n)
{
    __shared__ int lds[256];
    const int tid = threadIdx.x;
    const int base = blockIdx.x * 1024 + tid * 4;
    int v[4];
    #pragma unroll
    for (int k = 0; k < 4; ++k) v[k] = (base + k < n) ? in[base + k] : 0;
    int tsum = v[0] + v[1] + v[2] + v[3];
    lds[tid] = tsum;
    __syncthreads();
    for (int off = 1; off < 256; off <<= 1) {
        int t = (tid >= off) ? lds[tid - off] : 0;
        __syncthreads();
        lds[tid] += t;
        __syncthreads();
    }
    int excl = lds[tid] - tsum;
    #pragma unroll
    for (int k = 0; k < 4; ++k) {
        if (base + k < n) out[base + k] = excl;
        excl += v[k];
    }
    if (tid == 255) part[blockIdx.x] = lds[255];
}

__global__ void scan2(int* __restrict__ part, int nb)   // nb <= 1024
{
    __shared__ int lds[256];
    const int tid = threadIdx.x;
    const int base = tid * 4;
    int v[4];
    #pragma unroll
    for (int k = 0; k < 4; ++k) v[k] = (base + k < nb) ? part[base + k] : 0;
    int tsum = v[0] + v[1] + v[2] + v[3];
    lds[tid] = tsum;
    __syncthreads();
    for (int off = 1; off < 256; off <<= 1) {
        int t = (tid >= off) ? lds[tid - off] : 0;
        __syncthreads();
        lds[tid] += t;
        __syncthreads();
    }
    int excl = lds[tid] - tsum;
    #pragma unroll
    for (int k = 0; k < 4; ++k) {
        if (base + k < nb) part[base + k] = excl;
        excl += v[k];
    }
}

__global__ void scan3(int* __restrict__ off, const int* __restrict__ part, int n, int E)
{
    int i = blockIdx.x * 256 + threadIdx.x;
    if (i < n) off[i] += part[i >> 10];
    if (i == 0) off[n] = E;
}

// ---- fused attention: one 16-lane group per destination node ----------------
// No max-tracking (shift-invariant softmax; alphas O(1), clamped at 115 in exp2
// domain). p_rel*scale*log2e folded into q. 4-edge ILP per iteration.
// q loads and out stores are NON-TEMPORAL so the kv table stays L3-resident.
__device__ inline void attn_node(const int* __restrict__ csrc, int begin, int end,
                                 const unsigned short* __restrict__ kvt,
                                 const float qv[4], int j, float res[4])
{
    float ss = 0.f, a0 = 0.f, a1 = 0.f, a2 = 0.f, a3 = 0.f;

    for (int t = begin; t < end; t += 4) {
        bool v1 = (t + 1 < end), v2 = (t + 2 < end), v3 = (t + 3 < end);
        int s0 = csrc[t];
        int s1 = csrc[v1 ? t + 1 : t];
        int s2 = csrc[v2 ? t + 2 : t];
        int s3 = csrc[v3 ? t + 3 : t];
        uint4 k0 = *(const uint4*)(kvt + (long)s0 * 128 + j * 8);
        uint4 k1 = *(const uint4*)(kvt + (long)s1 * 128 + j * 8);
        uint4 k2 = *(const uint4*)(kvt + (long)s2 * 128 + j * 8);
        uint4 k3 = *(const uint4*)(kvt + (long)s3 * 128 + j * 8);

        float p0 = __uint_as_float(k0.x << 16) * qv[0] + __uint_as_float(k0.y << 16) * qv[1]
                 + __uint_as_float(k0.z << 16) * qv[2] + __uint_as_float(k0.w << 16) * qv[3];
        float p1 = __uint_as_float(k1.x << 16) * qv[0] + __uint_as_float(k1.y << 16) * qv[1]
                 + __uint_as_float(k1.z << 16) * qv[2] + __uint_as_float(k1.w << 16) * qv[3];
        float p2 = __uint_as_float(k2.x << 16) * qv[0] + __uint_as_float(k2.y << 16) * qv[1]
                 + __uint_as_float(k2.z << 16) * qv[2] + __uint_as_float(k2.w << 16) * qv[3];
        float p3 = __uint_as_float(k3.x << 16) * qv[0] + __uint_as_float(k3.y << 16) * qv[1]
                 + __uint_as_float(k3.z << 16) * qv[2] + __uint_as_float(k3.w << 16) * qv[3];

        p0 += __shfl_xor(p0, 1);  p1 += __shfl_xor(p1, 1);
        p2 += __shfl_xor(p2, 1);  p3 += __shfl_xor(p3, 1);
        p0 += __shfl_xor(p0, 2);  p1 += __shfl_xor(p1, 2);
        p2 += __shfl_xor(p2, 2);  p3 += __shfl_xor(p3, 2);
        p0 += __shfl_xor(p0, 4);  p1 += __shfl_xor(p1, 4);
        p2 += __shfl_xor(p2, 4);  p3 += __shfl_xor(p3, 4);

        float w0 = exp2f(fminf(p0, 115.f));
        float w1 = v1 ? exp2f(fminf(p1, 115.f)) : 0.f;
        float w2 = v2 ? exp2f(fminf(p2, 115.f)) : 0.f;
        float w3 = v3 ? exp2f(fminf(p3, 115.f)) : 0.f;

        ss += (w0 + w1) + (w2 + w3);
        a0 += w0 * __uint_as_float(k0.x & 0xffff0000u) + w1 * __uint_as_float(k1.x & 0xffff0000u)
            + w2 * __uint_as_float(k2.x & 0xffff0000u) + w3 * __uint_as_float(k3.x & 0xffff0000u);
        a1 += w0 * __uint_as_float(k0.y & 0xffff0000u) + w1 * __uint_as_float(k1.y & 0xffff0000u)
            + w2 * __uint_as_float(k2.y & 0xffff0000u) + w3 * __uint_as_float(k3.y & 0xffff0000u);
        a2 += w0 * __uint_as_float(k0.z & 0xffff0000u) + w1 * __uint_as_float(k1.z & 0xffff0000u)
            + w2 * __uint_as_float(k2.z & 0xffff0000u) + w3 * __uint_as_float(k3.z & 0xffff0000u);
        a3 += w0 * __uint_as_float(k0.w & 0xffff0000u) + w1 * __uint_as_float(k1.w & 0xffff0000u)
            + w2 * __uint_as_float(k2.w & 0xffff0000u) + w3 * __uint_as_float(k3.w & 0xffff0000u);
    }

    float inv = 1.f / (ss + 1e-16f);
    res[0] = a0 * inv; res[1] = a1 * inv; res[2] = a2 * inv; res[3] = a3 * inv;
}

__global__ void __launch_bounds__(256)
attn_all(const int* __restrict__ off, const int* __restrict__ csrc,
         const unsigned short* __restrict__ qbf, const unsigned short* __restrict__ kv,
         const float* __restrict__ prel, float scale, unsigned short* __restrict__ outb)
{
    const int tid = threadIdx.x;
    const int nid = blockIdx.x * 16 + (tid >> 4);   // 16 nodes per block
    const int j = tid & 15;
    const int h = j >> 3;
    const float l2e = 1.4426950408889634f;

    long row; int segA, segB = -1; long kbA, kbB = 0; float psA, psB = 0.f;
    if (nid < 100000) {
        row = nid;
        segA = nid;            kbA = c_rbase[0]; psA = prel[0 + h] * scale * l2e;
        segB = 500000 + nid;   kbB = c_rbase[3]; psB = prel[6 + h] * scale * l2e;
    } else if (nid < 300000) {
        int kk = nid - 100000;
        row = 300000 + kk;
        segA = 100000 + kk;    kbA = c_rbase[1]; psA = prel[2 + h] * scale * l2e;
    } else {
        int aa = nid - 300000;
        row = 100000 + aa;
        segA = 300000 + aa;    kbA = c_rbase[2]; psA = prel[4 + h] * scale * l2e;
    }

    // non-temporal q load (streaming; don't evict kv from L3)
    u32x2 qw = __builtin_nontemporal_load((const u32x2*)&qbf[row * 64 + 4 * j]);
    float qraw[4] = {bf2f((unsigned short)(qw.x & 0xffffu)),
                     bf2f((unsigned short)(qw.x >> 16)),
                     bf2f((unsigned short)(qw.y & 0xffffu)),
                     bf2f((unsigned short)(qw.y >> 16))};

    float res[4];
    {
        float qv[4] = {qraw[0] * psA, qraw[1] * psA, qraw[2] * psA, qraw[3] * psA};
        attn_node(csrc, off[segA], off[segA + 1], kv + kbA * 128, qv, j, res);
    }
    if (segB >= 0) {
        float qv[4] = {qraw[0] * psB, qraw[1] * psB, qraw[2] * psB, qraw[3] * psB};
        float r2[4];
        attn_node(csrc, off[segB], off[segB + 1], kv + kbB * 128, qv, j, r2);
        res[0] += r2[0]; res[1] += r2[1]; res[2] += r2[2]; res[3] += r2[3];
    }

    u32x2 o;
    o.x = (unsigned)f2bf(res[0]) | ((unsigned)f2bf(res[1]) << 16);
    o.y = (unsigned)f2bf(res[2]) | ((unsigned)f2bf(res[3]) << 16);
    __builtin_nontemporal_store(o, (u32x2*)&outb[row * 64 + 4 * j]);
}

// ---- link prediction (bf16 z gathers) ---------------------------------------
__global__ void pred_all(const int* __restrict__ psrc, const int* __restrict__ pdst,
                         const int* __restrict__ nsrc, const int* __restrict__ ndst,
                         const unsigned short* __restrict__ zb, float* __restrict__ out)
{
    int t = blockIdx.x * 256 + threadIdx.x;
    int g = t >> 3, lane = t & 7;
    if (g >= EPc + ENc) return;
    int s, d;
    if (g < EPc) { s = psrc[g]; d = pdst[g]; }
    else         { int gg = g - EPc; s = nsrc[gg]; d = ndst[gg]; }
    uint4 zs = *(const uint4*)&zb[(long)s * 64 + lane * 8];
    uint4 zd = *(const uint4*)&zb[(100000L + d) * 64 + lane * 8];
    float p = 0.f;
    p += bf2f((unsigned short)(zs.x & 0xffffu)) * bf2f((unsigned short)(zd.x & 0xffffu));
    p += bf2f((unsigned short)(zs.x >> 16))     * bf2f((unsigned short)(zd.x >> 16));
    p += bf2f((unsigned short)(zs.y & 0xffffu)) * bf2f((unsigned short)(zd.y & 0xffffu));
    p += bf2f((unsigned short)(zs.y >> 16))     * bf2f((unsigned short)(zd.y >> 16));
    p += bf2f((unsigned short)(zs.z & 0xffffu)) * bf2f((unsigned short)(zd.z & 0xffffu));
    p += bf2f((unsigned short)(zs.z >> 16))     * bf2f((unsigned short)(zd.z >> 16));
    p += bf2f((unsigned short)(zs.w & 0xffffu)) * bf2f((unsigned short)(zd.w & 0xffffu));
    p += bf2f((unsigned short)(zs.w >> 16))     * bf2f((unsigned short)(zd.w >> 16));
    p += __shfl_xor(p, 1);
    p += __shfl_xor(p, 2);
    p += __shfl_xor(p, 4);
    if (lane == 0) out[g] = 1.f / (1.f + expf(-p));
}

} // namespace

extern "C" void kernel_launch(void* const* d_in, const int* in_sizes, int n_in,
                              void* d_out, int out_size, void* d_ws, size_t ws_size,
                              hipStream_t stream)
{
    const float* xq    = (const float*)d_in[0];
    const float* xa    = (const float*)d_in[1];
    const float* xk    = (const float*)d_in[2];
    const float* lin_w = (const float*)d_in[3];
    const float* lin_b = (const float*)d_in[4];
    const float* k_w   = (const float*)d_in[5];
    const float* k_b   = (const float*)d_in[6];
    const float* q_w   = (const float*)d_in[7];
    const float* q_b   = (const float*)d_in[8];
    const float* v_w   = (const float*)d_in[9];
    const float* v_b   = (const float*)d_in[10];
    const float* a_w   = (const float*)d_in[11];
    const float* a_b   = (const float*)d_in[12];
    const float* a_rel = (const float*)d_in[13];
    const float* m_rel = (const float*)d_in[14];
    const float* p_rel = (const float*)d_in[15];
    const float* skip  = (const float*)d_in[16];
    const int* esrc[4] = {(const int*)d_in[17], (const int*)d_in[19], (const int*)d_in[21], (const int*)d_in[23]};
    const int* edst[4] = {(const int*)d_in[18], (const int*)d_in[20], (const int*)d_in[22], (const int*)d_in[24]};
    const int* pos_src = (const int*)d_in[25];
    const int* pos_dst = (const int*)d_in[26];
    const int* neg_src = (const int*)d_in[27];
    const int* neg_dst = (const int*)d_in[28];

    float* ws   = (float*)d_ws;
    float* outp = (float*)d_out;
    int*   wi   = (int*)(ws + INT_OFF);
    unsigned short* xsb  = (unsigned short*)(ws + XSB_OFF);
    unsigned short* outb = (unsigned short*)(ws + OUTB_OFF);
    unsigned short* qbf  = (unsigned short*)(ws + QBF_OFF);
    unsigned short* kvb  = (unsigned short*)(ws + KV_OFF);
    unsigned short* zbb  = (unsigned short*)(ws + ZB_OFF);
    unsigned short* wtb  = (unsigned short*)(ws + WTB_OFF);
    float*          wfb  = ws + WFB_OFF;

    // zero degree counters (memset-clean lines keep atomics fast)
    hipMemsetAsync(wi + DEG_I, 0, 600000L * sizeof(int), stream);

    // stage 1: fused rel weights + transposes + CSR count (stores per-edge rank)
    prep_count<<<196 + 9375, 256, 0, stream>>>(
        lin_w, q_w, a_w, k_w, k_b, v_w, v_b, a_rel, m_rel, wtb, wfb,
        edst[0], edst[1], edst[2], edst[3], wi + DEG_I, wi + RANK_I);

    // CSR offsets
    const int nb = (NSEG + 1023) / 1024;   // 586
    scan1<<<nb, 256, 0, stream>>>(wi + DEG_I, wi + OFFS_I, wi + PART_I, NSEG);
    scan2<<<1, 256, 0, stream>>>(wi + PART_I, nb);
    scan3<<<(NSEG + 255) / 256, 256, 0, stream>>>(wi + OFFS_I, wi + PART_I, NSEG, ETOT);

    // stage 2: lin GEMM + atomic-free CSR fill carried by every thread
    lin_fill<<<7813, 256, 0, stream>>>(
        esrc[0], edst[0], esrc[1], edst[1], esrc[2], edst[2], esrc[3], edst[3],
        wi + OFFS_I, wi + RANK_I, wi + CSRC_I,
        xq, xa, xk, wtb, lin_b, xsb);

    // q + kv as one-block-per-product
    qkv_split<<<8598, 256, 0, stream>>>(xsb, wtb, q_b, wfb, qbf, kvb);

    // merged attention: one 16-lane group per destination node
    const float scale = 0.17677669529663687f;   // 1/sqrt(32)
    attn_all<<<31250, 256, 0, stream>>>(wi + OFFS_I, wi + CSRC_I, qbf, kvb,
                                        p_rel, scale, outb);

    // output head (+ bf16 z copies for pred)
    head_mfma<<<3908, 256, 0, stream>>>(outb, xsb, wtb, a_b, skip, outp, zbb);

    // link predictions
    pred_all<<<(200000 * 8 + 255) / 256, 256, 0, stream>>>(
        pos_src, pos_dst, neg_src, neg_dst, zbb, outp);
}